// Round 14
// baseline (2125.588 us; speedup 1.0000x reference)
//
#include <hip/hip_runtime.h>
#include <math.h>

// Residual VQ, 4 stages, N=16384 rows, D=512, K=4096.
// Round 14: candidate compaction. passA's epilogue now compacts, per
// (row, 128-tile), the approx candidates with y^ <= tilemin+EPS (CAP=2,
// overflow -> sentinel) into gbuf. New fused passBC (thread-per-row) does the
// exact serial recheck of only ~2 candidates/row (was 128-cand tile recheck,
// 200x more work); overflow tiles (~0.06%) fall back to the round-13 passC.
// Containment: thr = gmin^+EPS <= tilemin^+EPS for every surviving tile, so
// all y^ <= thr are in the buffer or the tile is flagged overflow. EPS=1e-3
// >= 2*delta (delta <= 2.7e-4 bf16 bound), proven rounds 7-13.
// Exact-math invariants: one fmaf per d, d=0..511 ascending, per output;
// epilogue fl(fl(rsq-fl(2*dot))+cbsq) uncontracted; first-index ties;
// numpy pairwise rsq/cbsq tree; exact residual/q_ste chain in combine.

namespace {
constexpr int N_ROWS     = 16384;
constexpr int DIM        = 512;
constexpr int K_CODES    = 4096;
constexpr int NUM_STAGES = 4;

constexpr int KTILES = 32;            // 128 codes per tile
constexpr int LTS    = 72;            // passA LDS row stride (bf16 elems)
constexpr float EPS  = 1e-3f;         // candidate margin (proven rounds 7-13)
constexpr int CAP    = 2;             // compacted candidates per (row,tile)

constexpr int CROWS  = 32;            // fallback passC rows per batch
constexpr int CGRIDY = 8;             // fallback passC y-blocks per ktile
constexpr int WSTRC  = 68;            // fallback passC Ws row stride (dwords)
constexpr int RSTR   = 68;            // fallback passC Rs row stride (dwords)

// d_out layout (all read back as float32):
constexpr size_t Q_OFF    = 0;
constexpr size_t IDX_OFF  = (size_t)N_ROWS * DIM;                  // 8388608
constexpr size_t LOSS_OFF = IDX_OFF + (size_t)N_ROWS * NUM_STAGES; // 8454144

// ws layout (bytes), total ~64.3 MB:
constexpr size_t RES_OFF  = 0;                                    // 32 MB fp32 residual
constexpr size_t RH_OFF   = (size_t)N_ROWS * DIM * 4;             // +16 MB bf16 residual
constexpr size_t WH_OFF   = RH_OFF + (size_t)N_ROWS * DIM * 2;    // +4 MB bf16 codebook
constexpr size_t CBSQ_OFF = WH_OFF + (size_t)K_CODES * DIM * 2;   // +16 KB
constexpr size_t RSQ_OFF  = CBSQ_OFF + (size_t)K_CODES * 4;       // +64 KB
constexpr size_t PART_OFF = RSQ_OFF + (size_t)N_ROWS * 4;         // +2 MB tile mins
constexpr size_t GBUF_OFF = PART_OFF + (size_t)N_ROWS * KTILES * 4;       // +8 MB cand buf
constexpr size_t BCNT_OFF = GBUF_OFF + (size_t)N_ROWS * KTILES * CAP * 8; // +128 B
constexpr size_t BENT_OFF = BCNT_OFF + 128;                       // +2 MB overflow lists
constexpr size_t BEST_OFF = BENT_OFF + (size_t)KTILES * N_ROWS * 4; // +128 KB packed best

constexpr unsigned long long EMPTY_E = 0xFFFFFFFFFFFFFFFFull;
constexpr unsigned long long OVFL_E  = 0xFFFFFFFFFFFFFFFEull;
} // namespace

typedef short bf16x8 __attribute__((ext_vector_type(8)));
typedef float f32x4  __attribute__((ext_vector_type(4)));

__device__ __forceinline__ unsigned short f2bf(float x) {   // RNE fp32->bf16
    unsigned int u = __float_as_uint(x);
    return (unsigned short)((u + 0x7fffu + ((u >> 16) & 1u)) >> 16);
}

__device__ __forceinline__ float f4c(const float4& v, int q) {
    return q == 0 ? v.x : q == 1 ? v.y : q == 2 ? v.z : v.w;
}

// Register-based exact pairwise tree: v8[i] = row[lane + i*64], i=0..7.
__device__ __forceinline__ float rowsq_tree(const float v8[8], int lane) {
#pragma clang fp contract(off)
    float P[4];
#pragma unroll
    for (int b = 0; b < 4; ++b) {
        float xa = v8[2 * b];
        float xb = v8[2 * b + 1];
        float sa = xa * xa;
        float sb = xb * xb;
        float R  = sa + sb;
        float t  = R + __shfl_down(R, 16, 64);
        float u  = t + __shfl_down(t, 32, 64);
        float a  = u + __shfl_down(u, 8, 64);
        float c  = a + __shfl_down(a, 4, 64);
        float d  = c + __shfl_down(c, 2, 64);
        P[b]     = d + __shfl_down(d, 1, 64);
    }
    float s01 = P[0] + P[1];
    float s23 = P[2] + P[3];
    return s01 + s23;
}

// cbsq + codebook bf16 conversion, fused (one 8MB read).
__global__ __launch_bounds__(64)
void cbsq_wh_kernel(const float* __restrict__ cb, float* __restrict__ cb_sq,
                    unsigned short* __restrict__ wh, float* __restrict__ loss) {
    int k = blockIdx.x;
    int lane = threadIdx.x;
    const float* row = cb + (size_t)k * DIM;
    unsigned short* whp = wh + (size_t)k * DIM;
    float v8[8];
#pragma unroll
    for (int i = 0; i < 8; ++i) {
        float v = row[lane + i * 64];
        v8[i] = v;
        whp[lane + i * 64] = f2bf(v);
    }
    float s = rowsq_tree(v8, lane);
    if (lane == 0) cb_sq[k] = s;
    if (k == 0 && lane == 0) *loss = 0.0f;
}

// Stage-0 init: rh = bf16(input), rsq = pairwise(input), zero bcnt.
__global__ __launch_bounds__(256)
void init_kernel(const float* __restrict__ input,
                 unsigned short* __restrict__ rh,
                 float* __restrict__ rsq, int* __restrict__ bcnt) {
    const int t = threadIdx.x;
    if (blockIdx.x == 0 && t < KTILES) bcnt[t] = 0;
    const int lane = t & 63;
    const int sub  = t >> 6;
    const int row  = blockIdx.x * 4 + sub;
    const float* x = input + (size_t)row * DIM;
    unsigned short* rhp = rh + (size_t)row * DIM;
    float v8[8];
#pragma unroll
    for (int i = 0; i < 8; ++i) {
        int d = lane + i * 64;
        float v = x[d];
        v8[i] = v;
        rhp[d] = f2bf(v);
    }
    float s = rowsq_tree(v8, lane);
    if (lane == 0) rsq[row] = s;
}

// Pass A: 128x128x(BK=64) bf16 MFMA GEMM (round-9 main loop, proven) +
// epilogue candidate compaction: per (row,tile) collect y^ <= tilemin+EPS
// (CAP=2, overflow sentinel) into gbuf. sbuf/scnt alias dead At/Bt LDS.
__global__ __launch_bounds__(256, 2)
void passA_kernel(const unsigned short* __restrict__ rh,
                  const unsigned short* __restrict__ wh,
                  const float* __restrict__ cb_sq,
                  const float* __restrict__ rsq,
                  float* __restrict__ part,
                  unsigned long long* __restrict__ gbuf) {
    const int jb = blockIdx.x;              // ktile (fast: share A-panel in L2)
    const int mb = blockIdx.y;
    const int mbase = mb * 128;
    const int nbase = jb * 128;

    __shared__ __align__(16) unsigned short At[128 * LTS];
    __shared__ __align__(16) unsigned short Bt[128 * LTS];
    __shared__ float rowmin[128][2];

    const int t    = threadIdx.x;
    const int lane = t & 63;
    const int wid  = t >> 6;
    const int wr   = wid >> 1;              // wave row (0/1)
    const int wc   = wid & 1;               // wave col (0/1)

    f32x4 acc[4][4];
#pragma unroll
    for (int mi = 0; mi < 4; ++mi)
#pragma unroll
        for (int ni = 0; ni < 4; ++ni) acc[mi][ni] = (f32x4){0.f, 0.f, 0.f, 0.f};

    for (int k0 = 0; k0 < DIM; k0 += 64) {
#pragma unroll
        for (int p = 0; p < 4; ++p) {
            int idx = p * 256 + t;
            int row = idx >> 3;
            int d8  = idx & 7;
            uint4 va = *(const uint4*)(rh + (size_t)(mbase + row) * DIM + k0 + d8 * 8);
            *(uint4*)&At[row * LTS + d8 * 8] = va;
            uint4 vb = *(const uint4*)(wh + (size_t)(nbase + row) * DIM + k0 + d8 * 8);
            *(uint4*)&Bt[row * LTS + d8 * 8] = vb;
        }
        __syncthreads();

#pragma unroll
        for (int kk = 0; kk < 2; ++kk) {
            bf16x8 af[4], bfr[4];
#pragma unroll
            for (int mi = 0; mi < 4; ++mi)
                af[mi] = *(const bf16x8*)&At[(wr * 64 + mi * 16 + (lane & 15)) * LTS
                                             + kk * 32 + (lane >> 4) * 8];
#pragma unroll
            for (int ni = 0; ni < 4; ++ni)
                bfr[ni] = *(const bf16x8*)&Bt[(wc * 64 + ni * 16 + (lane & 15)) * LTS
                                              + kk * 32 + (lane >> 4) * 8];
#pragma unroll
            for (int mi = 0; mi < 4; ++mi)
#pragma unroll
                for (int ni = 0; ni < 4; ++ni)
                    acc[mi][ni] = __builtin_amdgcn_mfma_f32_16x16x32_bf16(
                        af[mi], bfr[ni], acc[mi][ni], 0, 0, 0);
        }
        __syncthreads();
    }

    // At/Bt are dead now: alias for compaction buffers.
    int* scnt = (int*)Bt;                               // [128]
    unsigned long long* sbuf = (unsigned long long*)At; // [128][CAP]
    if (t < 128) {
        scnt[t] = 0;
        sbuf[t * CAP + 0] = EMPTY_E;
        sbuf[t * CAP + 1] = EMPTY_E;
    }

    // Pass 1: per-row min over the wave's 64 cols, then cross-wave via LDS.
#pragma unroll
    for (int mi = 0; mi < 4; ++mi) {
#pragma unroll
        for (int reg = 0; reg < 4; ++reg) {
            int rloc = wr * 64 + mi * 16 + (lane >> 4) * 4 + reg;
            float rsqv = rsq[mbase + rloc];
            float m = INFINITY;
#pragma unroll
            for (int ni = 0; ni < 4; ++ni) {
                int kg = nbase + wc * 64 + ni * 16 + (lane & 15);
                float y;
                {
#pragma clang fp contract(off)
                    float t2 = 2.0f * acc[mi][ni][reg];
                    float u  = rsqv - t2;
                    y        = u + cb_sq[kg];
                }
                m = fminf(m, y);
            }
#pragma unroll
            for (int off = 1; off < 16; off <<= 1)
                m = fminf(m, __shfl_xor(m, off, 64));
            if ((lane & 15) == 0) rowmin[rloc][wc] = m;
        }
    }
    __syncthreads();

    // Pass 2: compact candidates with y <= tilemin + EPS (recompute y, same
    // rounding as pass 1).
#pragma unroll
    for (int mi = 0; mi < 4; ++mi) {
#pragma unroll
        for (int reg = 0; reg < 4; ++reg) {
            int rloc = wr * 64 + mi * 16 + (lane >> 4) * 4 + reg;
            float thrT = fminf(rowmin[rloc][0], rowmin[rloc][1]) + EPS;
            float rsqv = rsq[mbase + rloc];
#pragma unroll
            for (int ni = 0; ni < 4; ++ni) {
                int kg = nbase + wc * 64 + ni * 16 + (lane & 15);
                float y;
                {
#pragma clang fp contract(off)
                    float t2 = 2.0f * acc[mi][ni][reg];
                    float u  = rsqv - t2;
                    y        = u + cb_sq[kg];
                }
                if (y <= thrT) {
                    int pos = atomicAdd(&scnt[rloc], 1);
                    if (pos < CAP)
                        sbuf[rloc * CAP + pos] =
                            ((unsigned long long)__float_as_uint(y) << 32) |
                            (unsigned)kg;
                }
            }
        }
    }
    __syncthreads();

    if (t < 128) {
        part[(size_t)(mbase + t) * KTILES + jb] = fminf(rowmin[t][0], rowmin[t][1]);
        unsigned long long s0 = sbuf[t * CAP + 0];
        unsigned long long s1 = sbuf[t * CAP + 1];
        if (scnt[t] > CAP) s0 = OVFL_E;
        size_t bidx = ((size_t)(mbase + t) * KTILES + jb) * CAP;
        gbuf[bidx]     = s0;
        gbuf[bidx + 1] = s1;
    }
}

// Pass BC (fused): per row, thr = gmin+EPS; exact serial recheck of compacted
// candidates; overflow tiles -> worklist for the fallback passC.
__global__ __launch_bounds__(256)
void passBC_kernel(const float* __restrict__ res,
                   const float* __restrict__ cb,
                   const float* __restrict__ cb_sq,
                   const float* __restrict__ rsq,
                   const float* __restrict__ part,
                   const unsigned long long* __restrict__ gbuf,
                   int* __restrict__ bcnt, int* __restrict__ bent,
                   unsigned long long* __restrict__ best) {
    const int row = blockIdx.x * 256 + threadIdx.x;
    const float* p = part + (size_t)row * KTILES;
    float gmin = p[0];
#pragma unroll
    for (int j = 1; j < KTILES; ++j) gmin = fminf(gmin, p[j]);
    const float thr  = gmin + EPS;
    const float rsqv = rsq[row];
    const float* rr  = res + (size_t)row * DIM;

    float by = INFINITY; int bk = 0x7fffffff;

    for (int j = 0; j < KTILES; ++j) {
        if (p[j] > thr) continue;
        size_t bidx = ((size_t)row * KTILES + j) * CAP;
        unsigned long long s0 = gbuf[bidx];
        unsigned long long s1 = gbuf[bidx + 1];
        if (s0 == OVFL_E) {   // buffer overflowed: full-tile fallback
            int pos = atomicAdd(&bcnt[j], 1);
            bent[(size_t)j * N_ROWS + pos] = row;
            continue;
        }
#pragma unroll
        for (int sl = 0; sl < CAP; ++sl) {
            unsigned long long s = sl ? s1 : s0;
            float yh = __uint_as_float((unsigned)(s >> 32));
            if (!(yh <= thr)) continue;    // EMPTY unpacks to NaN -> skipped
            int k = (int)(s & 0xFFFFFFFFull);
            const float* wp = cb + (size_t)k * DIM;
            // Exact chain: one fmaf per d, d = 0..511 ascending.
            float dot = 0.0f;
#pragma unroll 4
            for (int d0 = 0; d0 < DIM; d0 += 8) {
                float4 r0 = *(const float4*)(rr + d0);
                float4 r1 = *(const float4*)(rr + d0 + 4);
                float4 w0 = *(const float4*)(wp + d0);
                float4 w1 = *(const float4*)(wp + d0 + 4);
                dot = fmaf(r0.x, w0.x, dot); dot = fmaf(r0.y, w0.y, dot);
                dot = fmaf(r0.z, w0.z, dot); dot = fmaf(r0.w, w0.w, dot);
                dot = fmaf(r1.x, w1.x, dot); dot = fmaf(r1.y, w1.y, dot);
                dot = fmaf(r1.z, w1.z, dot); dot = fmaf(r1.w, w1.w, dot);
            }
            float y;
            {
#pragma clang fp contract(off)
                float t2 = 2.0f * dot;
                float u  = rsqv - t2;
                y        = u + cb_sq[k];
            }
            if (y < by || (y == by && k < bk)) { by = y; bk = k; }
        }
    }
    best[row] = ((unsigned long long)__float_as_uint(by) << 32) | (unsigned)bk;
}

// Fallback pass C (round-13 verbatim): exact full-tile recheck of overflow
// entries. Expected ~hundreds of entries total.
__global__ __launch_bounds__(256)
void passC_kernel(const float* __restrict__ res,
                  const float* __restrict__ cb,
                  const float* __restrict__ cb_sq,
                  const float* __restrict__ rsq,
                  const int* __restrict__ bcnt, const int* __restrict__ bent,
                  unsigned long long* __restrict__ best) {
    const int j   = blockIdx.x;             // ktile
    const int cnt = bcnt[j];
    const int t   = threadIdx.x;
    const int cg  = t & 31;                 // cands cg*4 .. cg*4+3
    const int rg  = t >> 5;                 // rows  rg*4 .. rg*4+3

    __shared__ __align__(16) float Ws[128 * WSTRC];
    __shared__ __align__(16) float Rs[CROWS * RSTR];
    __shared__ int   rowl[CROWS];
    __shared__ float rsql[CROWS];

    for (int base = blockIdx.y * CROWS; base < cnt; base += gridDim.y * CROWS) {
        if (t < CROWS) {
            int e  = base + t;
            int rw = bent[(size_t)j * N_ROWS + (e < cnt ? e : cnt - 1)];
            rowl[t] = rw;
            rsql[t] = rsq[rw];
        }
        __syncthreads();
        const int nrows = min(CROWS, cnt - base);

        float acc[4][4];
#pragma unroll
        for (int ri = 0; ri < 4; ++ri)
#pragma unroll
            for (int q = 0; q < 4; ++q) acc[ri][q] = 0.0f;

        for (int d0 = 0; d0 < DIM; d0 += 64) {
#pragma unroll
            for (int p = 0; p < 8; ++p) {
                int idx  = p * 256 + t;
                int cand = idx >> 4;
                int d4   = idx & 15;
                float4 v = *(const float4*)(cb + (size_t)(j * 128 + cand) * DIM + d0 + d4 * 4);
                int s = d4 ^ ((cand >> 2) & 7) ^ ((cand >> 5) & 3);
                *(float4*)&Ws[cand * WSTRC + s * 4] = v;
            }
#pragma unroll
            for (int p = 0; p < 2; ++p) {
                int idx = p * 256 + t;
                int row = idx >> 4;
                int d4  = idx & 15;
                float4 v = *(const float4*)(res + (size_t)rowl[row] * DIM + d0 + d4 * 4);
                *(float4*)&Rs[row * RSTR + d4 * 4] = v;
            }
            __syncthreads();

#pragma unroll
            for (int dq = 0; dq < 16; ++dq) {
                const int s = dq ^ (cg & 7) ^ ((cg >> 3) & 3);
                float4 w4[4];
#pragma unroll
                for (int q = 0; q < 4; ++q)
                    w4[q] = *(const float4*)&Ws[(cg * 4 + q) * WSTRC + s * 4];
#pragma unroll
                for (int ri = 0; ri < 4; ++ri) {
                    float4 rf = *(const float4*)&Rs[(rg * 4 + ri) * RSTR + dq * 4];
#pragma unroll
                    for (int dd = 0; dd < 4; ++dd) {
                        float rv = f4c(rf, dd);
                        acc[ri][0] = fmaf(rv, f4c(w4[0], dd), acc[ri][0]);
                        acc[ri][1] = fmaf(rv, f4c(w4[1], dd), acc[ri][1]);
                        acc[ri][2] = fmaf(rv, f4c(w4[2], dd), acc[ri][2]);
                        acc[ri][3] = fmaf(rv, f4c(w4[3], dd), acc[ri][3]);
                    }
                }
            }
            __syncthreads();
        }

#pragma unroll
        for (int ri = 0; ri < 4; ++ri) {
            int rloc = rg * 4 + ri;
            float rsqv = rsql[rloc];
            float by = INFINITY; int bk = 0x7fffffff;
#pragma unroll
            for (int q = 0; q < 4; ++q) {
                int k = j * 128 + cg * 4 + q;
                float y;
                {
#pragma clang fp contract(off)
                    float t2 = 2.0f * acc[ri][q];
                    float u  = rsqv - t2;
                    y        = u + cb_sq[k];
                }
                if (y < by || (y == by && k < bk)) { by = y; bk = k; }
            }
#pragma unroll
            for (int off = 1; off < 32; off <<= 1) {
                float ov = __shfl_xor(by, off, 64);
                int   oi = __shfl_xor(bk, off, 64);
                if (ov < by || (ov == by && oi < bk)) { by = ov; bk = oi; }
            }
            if (cg == 0 && rloc < nrows) {
                unsigned long long pk =
                    ((unsigned long long)__float_as_uint(by) << 32) |
                    (unsigned long long)(unsigned)bk;
                atomicMin(&best[rowl[rloc]], pk);
            }
        }
        __syncthreads();
    }
}

// Combine: best index -> idx_out; exact fp32 residual/q_ste update; for the
// next stage also emit bf16 residual (rh), exact pairwise rsq, and zero bcnt.
__global__ __launch_bounds__(256)
void combine_kernel(float* __restrict__ res_out,
                    const float* __restrict__ res_in,
                    const float* __restrict__ cb,
                    const unsigned long long* __restrict__ best,
                    float* __restrict__ qout,
                    float* __restrict__ idx_out,
                    unsigned short* __restrict__ rh,
                    float* __restrict__ rsq,
                    int* __restrict__ bcnt,
                    int stage, int do_next) {
#pragma clang fp contract(off)
    const int t    = threadIdx.x;
    if (do_next && blockIdx.x == 0 && t < KTILES) bcnt[t] = 0;
    const int lane = t & 63;
    const int sub  = t >> 6;
    const int row  = blockIdx.x * 4 + sub;

    int bi = (int)(best[row] & 0xffffffffull);
    if (lane == 0) idx_out[(size_t)row * NUM_STAGES + stage] = (float)bi;

    const float* w   = cb + (size_t)bi * DIM;
    const float* rin = res_in + (size_t)row * DIM;
    float*       r   = res_out + (size_t)row * DIM;
    float*       q   = qout + (size_t)row * DIM;
    unsigned short* rhp = rh + (size_t)row * DIM;

    float rn8[8];
#pragma unroll
    for (int i = 0; i < DIM / 64; ++i) {
        int d = lane + i * 64;
        float wv = w[d];
        float rv = rin[d];
        float tq    = wv - rv;     // fl(q - r)
        float q_ste = rv + tq;     // fl(r + (q - r))
        float rn    = rv - q_ste;  // fl(r - q_ste)
        rn8[i] = rn;
        if (do_next) {
            r[d]   = rn;
            rhp[d] = f2bf(rn);
        }
        if (stage == 0) q[d] = q_ste;
        else            q[d] = q[d] + q_ste;   // stage-order fp32 accumulation
    }
    if (do_next) {
        float s = rowsq_tree(rn8, lane);
        if (lane == 0) rsq[row] = s;
    }
}

extern "C" void kernel_launch(void* const* d_in, const int* in_sizes, int n_in,
                              void* d_out, int out_size, void* d_ws, size_t ws_size,
                              hipStream_t stream) {
    const float* input = (const float*)d_in[0];
    const float* cb    = (const float*)d_in[1];

    float* out_f   = (float*)d_out;
    float* qout    = out_f + Q_OFF;
    float* idx_out = out_f + IDX_OFF;
    float* loss    = out_f + LOSS_OFF;

    char* ws = (char*)d_ws;
    float*          residual = (float*)(ws + RES_OFF);
    unsigned short* rh       = (unsigned short*)(ws + RH_OFF);
    unsigned short* wh       = (unsigned short*)(ws + WH_OFF);
    float*          cb_sq    = (float*)(ws + CBSQ_OFF);
    float*          rsq      = (float*)(ws + RSQ_OFF);
    float*          part     = (float*)(ws + PART_OFF);
    unsigned long long* gbuf = (unsigned long long*)(ws + GBUF_OFF);
    int*            bcnt     = (int*)(ws + BCNT_OFF);
    int*            bent     = (int*)(ws + BENT_OFF);
    unsigned long long* best = (unsigned long long*)(ws + BEST_OFF);

    cbsq_wh_kernel<<<K_CODES, 64, 0, stream>>>(cb, cb_sq, wh, loss);
    init_kernel<<<N_ROWS / 4, 256, 0, stream>>>(input, rh, rsq, bcnt);

    for (int s = 0; s < NUM_STAGES; ++s) {
        const float* rin = (s == 0) ? input : residual;
        passA_kernel<<<dim3(KTILES, N_ROWS / 128), 256, 0, stream>>>(
            rh, wh, cb_sq, rsq, part, gbuf);
        passBC_kernel<<<N_ROWS / 256, 256, 0, stream>>>(
            rin, cb, cb_sq, rsq, part, gbuf, bcnt, bent, best);
        passC_kernel<<<dim3(KTILES, CGRIDY), 256, 0, stream>>>(
            rin, cb, cb_sq, rsq, bcnt, bent, best);
        combine_kernel<<<N_ROWS / 4, 256, 0, stream>>>(
            residual, rin, cb, best, qout, idx_out, rh, rsq, bcnt,
            s, (s < NUM_STAGES - 1) ? 1 : 0);
    }
}

// Round 15
// 1205.176 us; speedup vs baseline: 1.7637x; 1.7637x over previous
//
#include <hip/hip_runtime.h>
#include <math.h>

// Residual VQ, 4 stages, N=16384 rows, D=512, K=4096.
// Round 15: compaction kept (r14 logic proved absmax=0), recheck re-engineered:
//   passB: lane-per-(row,tile) scan (8192 waves), pushes surviving compacted
//          candidates (row,k) to a dense worklist; overflow -> bent fallback.
//   passR: thread-per-entry exact recheck with depth-3 static-register
//          prefetch (r14's passBC was latency-dead: 256 waves, serial HBM
//          loads, 380us @ 2% VALUBusy).
//   passA (r14, proven), passC fallback (r13, proven), combine unchanged.
// Exact-math invariants: one fmaf per d, d=0..511 ascending, per output;
// epilogue fl(fl(rsq-fl(2*dot))+cbsq) uncontracted; first-index ties;
// numpy pairwise rsq/cbsq tree; exact residual/q_ste chain in combine.

namespace {
constexpr int N_ROWS     = 16384;
constexpr int DIM        = 512;
constexpr int K_CODES    = 4096;
constexpr int NUM_STAGES = 4;

constexpr int KTILES = 32;            // 128 codes per tile
constexpr int LTS    = 72;            // passA LDS row stride (bf16 elems)
constexpr float EPS  = 1e-3f;         // candidate margin (proven rounds 7-14)
constexpr int CAP    = 2;             // compacted candidates per (row,tile)
constexpr int WLCAP  = 131072;        // worklist capacity (overflow -> bent)

constexpr int CROWS  = 32;            // fallback passC rows per batch
constexpr int CGRIDY = 8;             // fallback passC y-blocks per ktile
constexpr int WSTRC  = 68;            // fallback passC Ws row stride (dwords)
constexpr int RSTR   = 68;            // fallback passC Rs row stride (dwords)

// d_out layout (all read back as float32):
constexpr size_t Q_OFF    = 0;
constexpr size_t IDX_OFF  = (size_t)N_ROWS * DIM;                  // 8388608
constexpr size_t LOSS_OFF = IDX_OFF + (size_t)N_ROWS * NUM_STAGES; // 8454144

// ws layout (bytes), total ~65.5 MB:
constexpr size_t RES_OFF  = 0;                                    // 32 MB fp32 residual
constexpr size_t RH_OFF   = (size_t)N_ROWS * DIM * 4;             // +16 MB bf16 residual
constexpr size_t WH_OFF   = RH_OFF + (size_t)N_ROWS * DIM * 2;    // +4 MB bf16 codebook
constexpr size_t CBSQ_OFF = WH_OFF + (size_t)K_CODES * DIM * 2;   // +16 KB
constexpr size_t RSQ_OFF  = CBSQ_OFF + (size_t)K_CODES * 4;       // +64 KB
constexpr size_t PART_OFF = RSQ_OFF + (size_t)N_ROWS * 4;         // +2 MB tile mins
constexpr size_t GBUF_OFF = PART_OFF + (size_t)N_ROWS * KTILES * 4;       // +8 MB cand buf
constexpr size_t BCNT_OFF = GBUF_OFF + (size_t)N_ROWS * KTILES * CAP * 8; // +128 B
constexpr size_t BENT_OFF = BCNT_OFF + 128;                       // +2 MB overflow lists
constexpr size_t BEST_OFF = BENT_OFF + (size_t)KTILES * N_ROWS * 4; // +128 KB packed best
constexpr size_t WLC_OFF  = BEST_OFF + (size_t)N_ROWS * 8;        // +128 B wl count
constexpr size_t WL_OFF   = WLC_OFF + 128;                        // +1 MB worklist

constexpr unsigned long long EMPTY_E = 0xFFFFFFFFFFFFFFFFull;
constexpr unsigned long long OVFL_E  = 0xFFFFFFFFFFFFFFFEull;
} // namespace

typedef short bf16x8 __attribute__((ext_vector_type(8)));
typedef float f32x4  __attribute__((ext_vector_type(4)));

__device__ __forceinline__ unsigned short f2bf(float x) {   // RNE fp32->bf16
    unsigned int u = __float_as_uint(x);
    return (unsigned short)((u + 0x7fffu + ((u >> 16) & 1u)) >> 16);
}

__device__ __forceinline__ float f4c(const float4& v, int q) {
    return q == 0 ? v.x : q == 1 ? v.y : q == 2 ? v.z : v.w;
}

// Register-based exact pairwise tree: v8[i] = row[lane + i*64], i=0..7.
__device__ __forceinline__ float rowsq_tree(const float v8[8], int lane) {
#pragma clang fp contract(off)
    float P[4];
#pragma unroll
    for (int b = 0; b < 4; ++b) {
        float xa = v8[2 * b];
        float xb = v8[2 * b + 1];
        float sa = xa * xa;
        float sb = xb * xb;
        float R  = sa + sb;
        float t  = R + __shfl_down(R, 16, 64);
        float u  = t + __shfl_down(t, 32, 64);
        float a  = u + __shfl_down(u, 8, 64);
        float c  = a + __shfl_down(a, 4, 64);
        float d  = c + __shfl_down(c, 2, 64);
        P[b]     = d + __shfl_down(d, 1, 64);
    }
    float s01 = P[0] + P[1];
    float s23 = P[2] + P[3];
    return s01 + s23;
}

// cbsq + codebook bf16 conversion, fused.
__global__ __launch_bounds__(64)
void cbsq_wh_kernel(const float* __restrict__ cb, float* __restrict__ cb_sq,
                    unsigned short* __restrict__ wh, float* __restrict__ loss) {
    int k = blockIdx.x;
    int lane = threadIdx.x;
    const float* row = cb + (size_t)k * DIM;
    unsigned short* whp = wh + (size_t)k * DIM;
    float v8[8];
#pragma unroll
    for (int i = 0; i < 8; ++i) {
        float v = row[lane + i * 64];
        v8[i] = v;
        whp[lane + i * 64] = f2bf(v);
    }
    float s = rowsq_tree(v8, lane);
    if (lane == 0) cb_sq[k] = s;
    if (k == 0 && lane == 0) *loss = 0.0f;
}

// Stage-0 init: rh = bf16(input), rsq = pairwise(input), zero bcnt/wlcnt.
__global__ __launch_bounds__(256)
void init_kernel(const float* __restrict__ input,
                 unsigned short* __restrict__ rh,
                 float* __restrict__ rsq, int* __restrict__ bcnt,
                 int* __restrict__ wlcnt) {
    const int t = threadIdx.x;
    if (blockIdx.x == 0 && t < KTILES) bcnt[t] = 0;
    if (blockIdx.x == 0 && t == KTILES) *wlcnt = 0;
    const int lane = t & 63;
    const int sub  = t >> 6;
    const int row  = blockIdx.x * 4 + sub;
    const float* x = input + (size_t)row * DIM;
    unsigned short* rhp = rh + (size_t)row * DIM;
    float v8[8];
#pragma unroll
    for (int i = 0; i < 8; ++i) {
        int d = lane + i * 64;
        float v = x[d];
        v8[i] = v;
        rhp[d] = f2bf(v);
    }
    float s = rowsq_tree(v8, lane);
    if (lane == 0) rsq[row] = s;
}

// Pass A: 128x128x(BK=64) bf16 MFMA GEMM + epilogue candidate compaction
// (round-14 verbatim, PASSED absmax=0).
__global__ __launch_bounds__(256, 2)
void passA_kernel(const unsigned short* __restrict__ rh,
                  const unsigned short* __restrict__ wh,
                  const float* __restrict__ cb_sq,
                  const float* __restrict__ rsq,
                  float* __restrict__ part,
                  unsigned long long* __restrict__ gbuf) {
    const int jb = blockIdx.x;
    const int mb = blockIdx.y;
    const int mbase = mb * 128;
    const int nbase = jb * 128;

    __shared__ __align__(16) unsigned short At[128 * LTS];
    __shared__ __align__(16) unsigned short Bt[128 * LTS];
    __shared__ float rowmin[128][2];

    const int t    = threadIdx.x;
    const int lane = t & 63;
    const int wid  = t >> 6;
    const int wr   = wid >> 1;
    const int wc   = wid & 1;

    f32x4 acc[4][4];
#pragma unroll
    for (int mi = 0; mi < 4; ++mi)
#pragma unroll
        for (int ni = 0; ni < 4; ++ni) acc[mi][ni] = (f32x4){0.f, 0.f, 0.f, 0.f};

    for (int k0 = 0; k0 < DIM; k0 += 64) {
#pragma unroll
        for (int p = 0; p < 4; ++p) {
            int idx = p * 256 + t;
            int row = idx >> 3;
            int d8  = idx & 7;
            uint4 va = *(const uint4*)(rh + (size_t)(mbase + row) * DIM + k0 + d8 * 8);
            *(uint4*)&At[row * LTS + d8 * 8] = va;
            uint4 vb = *(const uint4*)(wh + (size_t)(nbase + row) * DIM + k0 + d8 * 8);
            *(uint4*)&Bt[row * LTS + d8 * 8] = vb;
        }
        __syncthreads();

#pragma unroll
        for (int kk = 0; kk < 2; ++kk) {
            bf16x8 af[4], bfr[4];
#pragma unroll
            for (int mi = 0; mi < 4; ++mi)
                af[mi] = *(const bf16x8*)&At[(wr * 64 + mi * 16 + (lane & 15)) * LTS
                                             + kk * 32 + (lane >> 4) * 8];
#pragma unroll
            for (int ni = 0; ni < 4; ++ni)
                bfr[ni] = *(const bf16x8*)&Bt[(wc * 64 + ni * 16 + (lane & 15)) * LTS
                                              + kk * 32 + (lane >> 4) * 8];
#pragma unroll
            for (int mi = 0; mi < 4; ++mi)
#pragma unroll
                for (int ni = 0; ni < 4; ++ni)
                    acc[mi][ni] = __builtin_amdgcn_mfma_f32_16x16x32_bf16(
                        af[mi], bfr[ni], acc[mi][ni], 0, 0, 0);
        }
        __syncthreads();
    }

    int* scnt = (int*)Bt;
    unsigned long long* sbuf = (unsigned long long*)At;
    if (t < 128) {
        scnt[t] = 0;
        sbuf[t * CAP + 0] = EMPTY_E;
        sbuf[t * CAP + 1] = EMPTY_E;
    }

#pragma unroll
    for (int mi = 0; mi < 4; ++mi) {
#pragma unroll
        for (int reg = 0; reg < 4; ++reg) {
            int rloc = wr * 64 + mi * 16 + (lane >> 4) * 4 + reg;
            float rsqv = rsq[mbase + rloc];
            float m = INFINITY;
#pragma unroll
            for (int ni = 0; ni < 4; ++ni) {
                int kg = nbase + wc * 64 + ni * 16 + (lane & 15);
                float y;
                {
#pragma clang fp contract(off)
                    float t2 = 2.0f * acc[mi][ni][reg];
                    float u  = rsqv - t2;
                    y        = u + cb_sq[kg];
                }
                m = fminf(m, y);
            }
#pragma unroll
            for (int off = 1; off < 16; off <<= 1)
                m = fminf(m, __shfl_xor(m, off, 64));
            if ((lane & 15) == 0) rowmin[rloc][wc] = m;
        }
    }
    __syncthreads();

#pragma unroll
    for (int mi = 0; mi < 4; ++mi) {
#pragma unroll
        for (int reg = 0; reg < 4; ++reg) {
            int rloc = wr * 64 + mi * 16 + (lane >> 4) * 4 + reg;
            float thrT = fminf(rowmin[rloc][0], rowmin[rloc][1]) + EPS;
            float rsqv = rsq[mbase + rloc];
#pragma unroll
            for (int ni = 0; ni < 4; ++ni) {
                int kg = nbase + wc * 64 + ni * 16 + (lane & 15);
                float y;
                {
#pragma clang fp contract(off)
                    float t2 = 2.0f * acc[mi][ni][reg];
                    float u  = rsqv - t2;
                    y        = u + cb_sq[kg];
                }
                if (y <= thrT) {
                    int pos = atomicAdd(&scnt[rloc], 1);
                    if (pos < CAP)
                        sbuf[rloc * CAP + pos] =
                            ((unsigned long long)__float_as_uint(y) << 32) |
                            (unsigned)kg;
                }
            }
        }
    }
    __syncthreads();

    if (t < 128) {
        part[(size_t)(mbase + t) * KTILES + jb] = fminf(rowmin[t][0], rowmin[t][1]);
        unsigned long long s0 = sbuf[t * CAP + 0];
        unsigned long long s1 = sbuf[t * CAP + 1];
        if (scnt[t] > CAP) s0 = OVFL_E;
        size_t bidx = ((size_t)(mbase + t) * KTILES + jb) * CAP;
        gbuf[bidx]     = s0;
        gbuf[bidx + 1] = s1;
    }
}

// Pass B: lane-per-(row,tile). 32 lanes scan one row's tile mins (coalesced),
// min via shfl width-32; surviving lanes read their gbuf slots and push
// (row,k) to the worklist. Overflow (sbuf or wl) -> bent full-tile fallback.
__global__ __launch_bounds__(256)
void passB_kernel(const float* __restrict__ part,
                  const unsigned long long* __restrict__ gbuf,
                  int* __restrict__ bcnt, int* __restrict__ bent,
                  int* __restrict__ wlcnt, int2* __restrict__ wl,
                  unsigned long long* __restrict__ best) {
    const int t    = threadIdx.x;
    const int jr   = t & 31;                  // tile index
    const int rsub = t >> 5;                  // 0..7
    const int row  = blockIdx.x * 8 + rsub;

    float pv = part[(size_t)row * KTILES + jr];
    float m = pv;
#pragma unroll
    for (int off = 1; off < 32; off <<= 1)
        m = fminf(m, __shfl_xor(m, off, 32));  // width 32: stays in this row
    float thr = m + EPS;
    if (jr == 0) best[row] = ~0ull;

    if (pv <= thr) {
        size_t bidx = ((size_t)row * KTILES + jr) * CAP;
        unsigned long long s0 = gbuf[bidx];
        unsigned long long s1 = gbuf[bidx + 1];
        bool fellback = false;
        if (s0 == OVFL_E) {
            int pos = atomicAdd(&bcnt[jr], 1);
            bent[(size_t)jr * N_ROWS + pos] = row;
            fellback = true;
        } else {
#pragma unroll
            for (int sl = 0; sl < CAP; ++sl) {
                unsigned long long s = sl ? s1 : s0;
                float yh = __uint_as_float((unsigned)(s >> 32));
                if (!(yh <= thr)) continue;   // EMPTY -> NaN -> skipped
                int k = (int)(s & 0xFFFFFFFFull);
                int pos = atomicAdd(wlcnt, 1);
                if (pos < WLCAP) {
                    wl[pos] = make_int2(row, k);
                } else if (!fellback) {       // wl full: full-tile fallback
                    int bp = atomicAdd(&bcnt[jr], 1);
                    bent[(size_t)jr * N_ROWS + bp] = row;
                    fellback = true;
                }
            }
        }
    }
}

#define CHAIN8(R0, W0, R1, W1)                                               \
    dot = fmaf((R0).x, (W0).x, dot); dot = fmaf((R0).y, (W0).y, dot);        \
    dot = fmaf((R0).z, (W0).z, dot); dot = fmaf((R0).w, (W0).w, dot);        \
    dot = fmaf((R1).x, (W1).x, dot); dot = fmaf((R1).y, (W1).y, dot);        \
    dot = fmaf((R1).z, (W1).z, dot); dot = fmaf((R1).w, (W1).w, dot);

#define LOADB(R0, W0, R1, W1, off)                                           \
    if ((off) < DIM) {                                                       \
        R0 = *(const float4*)(rr + (off));                                   \
        W0 = *(const float4*)(wp + (off));                                   \
        R1 = *(const float4*)(rr + (off) + 4);                               \
        W1 = *(const float4*)(wp + (off) + 4);                               \
    }

// Pass R: thread-per-entry exact recheck, depth-3 static-register prefetch.
// Chain: one fmaf per d, d = 0..511 ascending -> bit-exact.
__global__ __launch_bounds__(256)
void passR_kernel(const float* __restrict__ res,
                  const float* __restrict__ cb,
                  const float* __restrict__ cb_sq,
                  const float* __restrict__ rsq,
                  const int* __restrict__ wlcnt, const int2* __restrict__ wl,
                  unsigned long long* __restrict__ best) {
    int cnt = *wlcnt;
    if (cnt > WLCAP) cnt = WLCAP;
    int e = blockIdx.x * 256 + threadIdx.x;
    if (e >= cnt) return;

    int2 en = wl[e];
    const int row = en.x;
    const int k   = en.y;
    const float* rr = res + (size_t)row * DIM;
    const float* wp = cb + (size_t)k * DIM;

    float4 ar0, aw0, ar1, aw1, br0, bw0, br1, bw1;
    float4 cr0, cw0, cr1, cw1, dr0, dw0, dr1, dw1;
    float dot = 0.0f;

    LOADB(ar0, aw0, ar1, aw1, 0)
    LOADB(br0, bw0, br1, bw1, 8)
    LOADB(cr0, cw0, cr1, cw1, 16)
    for (int d0 = 0; d0 < DIM; d0 += 32) {
        LOADB(dr0, dw0, dr1, dw1, d0 + 24)
        CHAIN8(ar0, aw0, ar1, aw1)
        LOADB(ar0, aw0, ar1, aw1, d0 + 32)
        CHAIN8(br0, bw0, br1, bw1)
        LOADB(br0, bw0, br1, bw1, d0 + 40)
        CHAIN8(cr0, cw0, cr1, cw1)
        LOADB(cr0, cw0, cr1, cw1, d0 + 48)
        CHAIN8(dr0, dw0, dr1, dw1)
    }

    float y;
    {
#pragma clang fp contract(off)
        float t2 = 2.0f * dot;
        float u  = rsq[row] - t2;
        y        = u + cb_sq[k];
    }
    unsigned long long pk =
        ((unsigned long long)__float_as_uint(y) << 32) | (unsigned)k;
    atomicMin(&best[row], pk);
}

// Fallback pass C (round-13 verbatim): exact full-tile recheck of overflow
// entries (expected ~hundreds total).
__global__ __launch_bounds__(256)
void passC_kernel(const float* __restrict__ res,
                  const float* __restrict__ cb,
                  const float* __restrict__ cb_sq,
                  const float* __restrict__ rsq,
                  const int* __restrict__ bcnt, const int* __restrict__ bent,
                  unsigned long long* __restrict__ best) {
    const int j   = blockIdx.x;
    const int cnt = bcnt[j];
    const int t   = threadIdx.x;
    const int cg  = t & 31;
    const int rg  = t >> 5;

    __shared__ __align__(16) float Ws[128 * WSTRC];
    __shared__ __align__(16) float Rs[CROWS * RSTR];
    __shared__ int   rowl[CROWS];
    __shared__ float rsql[CROWS];

    for (int base = blockIdx.y * CROWS; base < cnt; base += gridDim.y * CROWS) {
        if (t < CROWS) {
            int e  = base + t;
            int rw = bent[(size_t)j * N_ROWS + (e < cnt ? e : cnt - 1)];
            rowl[t] = rw;
            rsql[t] = rsq[rw];
        }
        __syncthreads();
        const int nrows = min(CROWS, cnt - base);

        float acc[4][4];
#pragma unroll
        for (int ri = 0; ri < 4; ++ri)
#pragma unroll
            for (int q = 0; q < 4; ++q) acc[ri][q] = 0.0f;

        for (int d0 = 0; d0 < DIM; d0 += 64) {
#pragma unroll
            for (int p = 0; p < 8; ++p) {
                int idx  = p * 256 + t;
                int cand = idx >> 4;
                int d4   = idx & 15;
                float4 v = *(const float4*)(cb + (size_t)(j * 128 + cand) * DIM + d0 + d4 * 4);
                int s = d4 ^ ((cand >> 2) & 7) ^ ((cand >> 5) & 3);
                *(float4*)&Ws[cand * WSTRC + s * 4] = v;
            }
#pragma unroll
            for (int p = 0; p < 2; ++p) {
                int idx = p * 256 + t;
                int row = idx >> 4;
                int d4  = idx & 15;
                float4 v = *(const float4*)(res + (size_t)rowl[row] * DIM + d0 + d4 * 4);
                *(float4*)&Rs[row * RSTR + d4 * 4] = v;
            }
            __syncthreads();

#pragma unroll
            for (int dq = 0; dq < 16; ++dq) {
                const int s = dq ^ (cg & 7) ^ ((cg >> 3) & 3);
                float4 w4[4];
#pragma unroll
                for (int q = 0; q < 4; ++q)
                    w4[q] = *(const float4*)&Ws[(cg * 4 + q) * WSTRC + s * 4];
#pragma unroll
                for (int ri = 0; ri < 4; ++ri) {
                    float4 rf = *(const float4*)&Rs[(rg * 4 + ri) * RSTR + dq * 4];
#pragma unroll
                    for (int dd = 0; dd < 4; ++dd) {
                        float rv = f4c(rf, dd);
                        acc[ri][0] = fmaf(rv, f4c(w4[0], dd), acc[ri][0]);
                        acc[ri][1] = fmaf(rv, f4c(w4[1], dd), acc[ri][1]);
                        acc[ri][2] = fmaf(rv, f4c(w4[2], dd), acc[ri][2]);
                        acc[ri][3] = fmaf(rv, f4c(w4[3], dd), acc[ri][3]);
                    }
                }
            }
            __syncthreads();
        }

#pragma unroll
        for (int ri = 0; ri < 4; ++ri) {
            int rloc = rg * 4 + ri;
            float rsqv = rsql[rloc];
            float by = INFINITY; int bk = 0x7fffffff;
#pragma unroll
            for (int q = 0; q < 4; ++q) {
                int k = j * 128 + cg * 4 + q;
                float y;
                {
#pragma clang fp contract(off)
                    float t2 = 2.0f * acc[ri][q];
                    float u  = rsqv - t2;
                    y        = u + cb_sq[k];
                }
                if (y < by || (y == by && k < bk)) { by = y; bk = k; }
            }
#pragma unroll
            for (int off = 1; off < 32; off <<= 1) {
                float ov = __shfl_xor(by, off, 64);
                int   oi = __shfl_xor(bk, off, 64);
                if (ov < by || (ov == by && oi < bk)) { by = ov; bk = oi; }
            }
            if (cg == 0 && rloc < nrows) {
                unsigned long long pk =
                    ((unsigned long long)__float_as_uint(by) << 32) |
                    (unsigned long long)(unsigned)bk;
                atomicMin(&best[rowl[rloc]], pk);
            }
        }
        __syncthreads();
    }
}

// Combine: best index -> idx_out; exact fp32 residual/q_ste update; for the
// next stage also emit rh, rsq, and zero bcnt/wlcnt.
__global__ __launch_bounds__(256)
void combine_kernel(float* __restrict__ res_out,
                    const float* __restrict__ res_in,
                    const float* __restrict__ cb,
                    const unsigned long long* __restrict__ best,
                    float* __restrict__ qout,
                    float* __restrict__ idx_out,
                    unsigned short* __restrict__ rh,
                    float* __restrict__ rsq,
                    int* __restrict__ bcnt, int* __restrict__ wlcnt,
                    int stage, int do_next) {
#pragma clang fp contract(off)
    const int t    = threadIdx.x;
    if (do_next && blockIdx.x == 0 && t < KTILES) bcnt[t] = 0;
    if (do_next && blockIdx.x == 0 && t == KTILES) *wlcnt = 0;
    const int lane = t & 63;
    const int sub  = t >> 6;
    const int row  = blockIdx.x * 4 + sub;

    int bi = (int)(best[row] & 0xffffffffull);
    if (lane == 0) idx_out[(size_t)row * NUM_STAGES + stage] = (float)bi;

    const float* w   = cb + (size_t)bi * DIM;
    const float* rin = res_in + (size_t)row * DIM;
    float*       r   = res_out + (size_t)row * DIM;
    float*       q   = qout + (size_t)row * DIM;
    unsigned short* rhp = rh + (size_t)row * DIM;

    float rn8[8];
#pragma unroll
    for (int i = 0; i < DIM / 64; ++i) {
        int d = lane + i * 64;
        float wv = w[d];
        float rv = rin[d];
        float tq    = wv - rv;     // fl(q - r)
        float q_ste = rv + tq;     // fl(r + (q - r))
        float rn    = rv - q_ste;  // fl(r - q_ste)
        rn8[i] = rn;
        if (do_next) {
            r[d]   = rn;
            rhp[d] = f2bf(rn);
        }
        if (stage == 0) q[d] = q_ste;
        else            q[d] = q[d] + q_ste;
    }
    if (do_next) {
        float s = rowsq_tree(rn8, lane);
        if (lane == 0) rsq[row] = s;
    }
}

extern "C" void kernel_launch(void* const* d_in, const int* in_sizes, int n_in,
                              void* d_out, int out_size, void* d_ws, size_t ws_size,
                              hipStream_t stream) {
    const float* input = (const float*)d_in[0];
    const float* cb    = (const float*)d_in[1];

    float* out_f   = (float*)d_out;
    float* qout    = out_f + Q_OFF;
    float* idx_out = out_f + IDX_OFF;
    float* loss    = out_f + LOSS_OFF;

    char* ws = (char*)d_ws;
    float*          residual = (float*)(ws + RES_OFF);
    unsigned short* rh       = (unsigned short*)(ws + RH_OFF);
    unsigned short* wh       = (unsigned short*)(ws + WH_OFF);
    float*          cb_sq    = (float*)(ws + CBSQ_OFF);
    float*          rsq      = (float*)(ws + RSQ_OFF);
    float*          part     = (float*)(ws + PART_OFF);
    unsigned long long* gbuf = (unsigned long long*)(ws + GBUF_OFF);
    int*            bcnt     = (int*)(ws + BCNT_OFF);
    int*            bent     = (int*)(ws + BENT_OFF);
    unsigned long long* best = (unsigned long long*)(ws + BEST_OFF);
    int*            wlcnt    = (int*)(ws + WLC_OFF);
    int2*           wl       = (int2*)(ws + WL_OFF);

    cbsq_wh_kernel<<<K_CODES, 64, 0, stream>>>(cb, cb_sq, wh, loss);
    init_kernel<<<N_ROWS / 4, 256, 0, stream>>>(input, rh, rsq, bcnt, wlcnt);

    for (int s = 0; s < NUM_STAGES; ++s) {
        const float* rin = (s == 0) ? input : residual;
        passA_kernel<<<dim3(KTILES, N_ROWS / 128), 256, 0, stream>>>(
            rh, wh, cb_sq, rsq, part, gbuf);
        passB_kernel<<<N_ROWS / 8, 256, 0, stream>>>(
            part, gbuf, bcnt, bent, wlcnt, wl, best);
        passR_kernel<<<WLCAP / 256, 256, 0, stream>>>(
            rin, cb, cb_sq, rsq, wlcnt, wl, best);
        passC_kernel<<<dim3(KTILES, CGRIDY), 256, 0, stream>>>(
            rin, cb, cb_sq, rsq, bcnt, bent, best);
        combine_kernel<<<N_ROWS / 4, 256, 0, stream>>>(
            residual, rin, cb, best, qout, idx_out, rh, rsq, bcnt, wlcnt,
            s, (s < NUM_STAGES - 1) ? 1 : 0);
    }
}

// Round 16
// 962.970 us; speedup vs baseline: 2.2073x; 1.2515x over previous
//
#include <hip/hip_runtime.h>
#include <math.h>

// Residual VQ, 4 stages, N=16384 rows, D=512, K=4096.
// Round 16: fuse passB+passR into passBC (r15's worklist had a single-address
// global atomicAdd hotspot + passR ran at 391 waves = zero TLP). passBC keeps
// the lane-per-(row,tile) layout (2048 blocks); surviving lanes run their <=2
// exact chains inline; width-32 packed-u64 shfl reduce; plain best store.
// part/gbuf transposed to [tile][row] so passA's epilogue writes are
// contiguous (kills cross-XCD partial-line write amplification).
// Exact-math invariants (verified rounds 3-15): one fmaf per d, d=0..511
// ascending, per output; epilogue fl(fl(rsq-fl(2*dot))+cbsq) uncontracted;
// first-index ties; numpy pairwise rsq/cbsq tree; exact residual/q_ste chain.

namespace {
constexpr int N_ROWS     = 16384;
constexpr int DIM        = 512;
constexpr int K_CODES    = 4096;
constexpr int NUM_STAGES = 4;

constexpr int KTILES = 32;            // 128 codes per tile
constexpr int LTS    = 72;            // passA LDS row stride (bf16 elems)
constexpr float EPS  = 1e-3f;         // candidate margin (proven rounds 7-15)
constexpr int CAP    = 2;             // compacted candidates per (row,tile)

constexpr int CROWS  = 32;            // fallback passC rows per batch
constexpr int CGRIDY = 8;             // fallback passC y-blocks per ktile
constexpr int WSTRC  = 68;            // fallback passC Ws row stride (dwords)
constexpr int RSTR   = 68;            // fallback passC Rs row stride (dwords)

// d_out layout (all read back as float32):
constexpr size_t Q_OFF    = 0;
constexpr size_t IDX_OFF  = (size_t)N_ROWS * DIM;                  // 8388608
constexpr size_t LOSS_OFF = IDX_OFF + (size_t)N_ROWS * NUM_STAGES; // 8454144

// ws layout (bytes), total ~64.3 MB:
constexpr size_t RES_OFF  = 0;                                    // 32 MB fp32 residual
constexpr size_t RH_OFF   = (size_t)N_ROWS * DIM * 4;             // +16 MB bf16 residual
constexpr size_t WH_OFF   = RH_OFF + (size_t)N_ROWS * DIM * 2;    // +4 MB bf16 codebook
constexpr size_t CBSQ_OFF = WH_OFF + (size_t)K_CODES * DIM * 2;   // +16 KB
constexpr size_t RSQ_OFF  = CBSQ_OFF + (size_t)K_CODES * 4;       // +64 KB
constexpr size_t PART_OFF = RSQ_OFF + (size_t)N_ROWS * 4;         // +2 MB tile mins [tile][row]
constexpr size_t GBUF_OFF = PART_OFF + (size_t)N_ROWS * KTILES * 4;       // +8 MB [tile][row][CAP]
constexpr size_t BCNT_OFF = GBUF_OFF + (size_t)N_ROWS * KTILES * CAP * 8; // +128 B
constexpr size_t BENT_OFF = BCNT_OFF + 128;                       // +2 MB overflow lists
constexpr size_t BEST_OFF = BENT_OFF + (size_t)KTILES * N_ROWS * 4; // +128 KB packed best

constexpr unsigned long long EMPTY_E = 0xFFFFFFFFFFFFFFFFull;
constexpr unsigned long long OVFL_E  = 0xFFFFFFFFFFFFFFFEull;
} // namespace

typedef short bf16x8 __attribute__((ext_vector_type(8)));
typedef float f32x4  __attribute__((ext_vector_type(4)));

__device__ __forceinline__ unsigned short f2bf(float x) {   // RNE fp32->bf16
    unsigned int u = __float_as_uint(x);
    return (unsigned short)((u + 0x7fffu + ((u >> 16) & 1u)) >> 16);
}

__device__ __forceinline__ float f4c(const float4& v, int q) {
    return q == 0 ? v.x : q == 1 ? v.y : q == 2 ? v.z : v.w;
}

// Register-based exact pairwise tree: v8[i] = row[lane + i*64], i=0..7.
__device__ __forceinline__ float rowsq_tree(const float v8[8], int lane) {
#pragma clang fp contract(off)
    float P[4];
#pragma unroll
    for (int b = 0; b < 4; ++b) {
        float xa = v8[2 * b];
        float xb = v8[2 * b + 1];
        float sa = xa * xa;
        float sb = xb * xb;
        float R  = sa + sb;
        float t  = R + __shfl_down(R, 16, 64);
        float u  = t + __shfl_down(t, 32, 64);
        float a  = u + __shfl_down(u, 8, 64);
        float c  = a + __shfl_down(a, 4, 64);
        float d  = c + __shfl_down(c, 2, 64);
        P[b]     = d + __shfl_down(d, 1, 64);
    }
    float s01 = P[0] + P[1];
    float s23 = P[2] + P[3];
    return s01 + s23;
}

// cbsq + codebook bf16 conversion, fused.
__global__ __launch_bounds__(64)
void cbsq_wh_kernel(const float* __restrict__ cb, float* __restrict__ cb_sq,
                    unsigned short* __restrict__ wh, float* __restrict__ loss) {
    int k = blockIdx.x;
    int lane = threadIdx.x;
    const float* row = cb + (size_t)k * DIM;
    unsigned short* whp = wh + (size_t)k * DIM;
    float v8[8];
#pragma unroll
    for (int i = 0; i < 8; ++i) {
        float v = row[lane + i * 64];
        v8[i] = v;
        whp[lane + i * 64] = f2bf(v);
    }
    float s = rowsq_tree(v8, lane);
    if (lane == 0) cb_sq[k] = s;
    if (k == 0 && lane == 0) *loss = 0.0f;
}

// Stage-0 init: rh = bf16(input), rsq = pairwise(input), zero bcnt.
__global__ __launch_bounds__(256)
void init_kernel(const float* __restrict__ input,
                 unsigned short* __restrict__ rh,
                 float* __restrict__ rsq, int* __restrict__ bcnt) {
    const int t = threadIdx.x;
    if (blockIdx.x == 0 && t < KTILES) bcnt[t] = 0;
    const int lane = t & 63;
    const int sub  = t >> 6;
    const int row  = blockIdx.x * 4 + sub;
    const float* x = input + (size_t)row * DIM;
    unsigned short* rhp = rh + (size_t)row * DIM;
    float v8[8];
#pragma unroll
    for (int i = 0; i < 8; ++i) {
        int d = lane + i * 64;
        float v = x[d];
        v8[i] = v;
        rhp[d] = f2bf(v);
    }
    float s = rowsq_tree(v8, lane);
    if (lane == 0) rsq[row] = s;
}

// Pass A: 128x128x(BK=64) bf16 MFMA GEMM + epilogue candidate compaction.
// part/gbuf in [tile][row] layout -> contiguous epilogue writes.
__global__ __launch_bounds__(256, 2)
void passA_kernel(const unsigned short* __restrict__ rh,
                  const unsigned short* __restrict__ wh,
                  const float* __restrict__ cb_sq,
                  const float* __restrict__ rsq,
                  float* __restrict__ part,
                  unsigned long long* __restrict__ gbuf) {
    const int jb = blockIdx.x;
    const int mb = blockIdx.y;
    const int mbase = mb * 128;
    const int nbase = jb * 128;

    __shared__ __align__(16) unsigned short At[128 * LTS];
    __shared__ __align__(16) unsigned short Bt[128 * LTS];
    __shared__ float rowmin[128][2];

    const int t    = threadIdx.x;
    const int lane = t & 63;
    const int wid  = t >> 6;
    const int wr   = wid >> 1;
    const int wc   = wid & 1;

    f32x4 acc[4][4];
#pragma unroll
    for (int mi = 0; mi < 4; ++mi)
#pragma unroll
        for (int ni = 0; ni < 4; ++ni) acc[mi][ni] = (f32x4){0.f, 0.f, 0.f, 0.f};

    for (int k0 = 0; k0 < DIM; k0 += 64) {
#pragma unroll
        for (int p = 0; p < 4; ++p) {
            int idx = p * 256 + t;
            int row = idx >> 3;
            int d8  = idx & 7;
            uint4 va = *(const uint4*)(rh + (size_t)(mbase + row) * DIM + k0 + d8 * 8);
            *(uint4*)&At[row * LTS + d8 * 8] = va;
            uint4 vb = *(const uint4*)(wh + (size_t)(nbase + row) * DIM + k0 + d8 * 8);
            *(uint4*)&Bt[row * LTS + d8 * 8] = vb;
        }
        __syncthreads();

#pragma unroll
        for (int kk = 0; kk < 2; ++kk) {
            bf16x8 af[4], bfr[4];
#pragma unroll
            for (int mi = 0; mi < 4; ++mi)
                af[mi] = *(const bf16x8*)&At[(wr * 64 + mi * 16 + (lane & 15)) * LTS
                                             + kk * 32 + (lane >> 4) * 8];
#pragma unroll
            for (int ni = 0; ni < 4; ++ni)
                bfr[ni] = *(const bf16x8*)&Bt[(wc * 64 + ni * 16 + (lane & 15)) * LTS
                                              + kk * 32 + (lane >> 4) * 8];
#pragma unroll
            for (int mi = 0; mi < 4; ++mi)
#pragma unroll
                for (int ni = 0; ni < 4; ++ni)
                    acc[mi][ni] = __builtin_amdgcn_mfma_f32_16x16x32_bf16(
                        af[mi], bfr[ni], acc[mi][ni], 0, 0, 0);
        }
        __syncthreads();
    }

    int* scnt = (int*)Bt;
    unsigned long long* sbuf = (unsigned long long*)At;
    if (t < 128) {
        scnt[t] = 0;
        sbuf[t * CAP + 0] = EMPTY_E;
        sbuf[t * CAP + 1] = EMPTY_E;
    }

    // Pass 1: per-row tile min.
#pragma unroll
    for (int mi = 0; mi < 4; ++mi) {
#pragma unroll
        for (int reg = 0; reg < 4; ++reg) {
            int rloc = wr * 64 + mi * 16 + (lane >> 4) * 4 + reg;
            float rsqv = rsq[mbase + rloc];
            float m = INFINITY;
#pragma unroll
            for (int ni = 0; ni < 4; ++ni) {
                int kg = nbase + wc * 64 + ni * 16 + (lane & 15);
                float y;
                {
#pragma clang fp contract(off)
                    float t2 = 2.0f * acc[mi][ni][reg];
                    float u  = rsqv - t2;
                    y        = u + cb_sq[kg];
                }
                m = fminf(m, y);
            }
#pragma unroll
            for (int off = 1; off < 16; off <<= 1)
                m = fminf(m, __shfl_xor(m, off, 64));
            if ((lane & 15) == 0) rowmin[rloc][wc] = m;
        }
    }
    __syncthreads();

    // Pass 2: compact candidates with y <= tilemin + EPS.
#pragma unroll
    for (int mi = 0; mi < 4; ++mi) {
#pragma unroll
        for (int reg = 0; reg < 4; ++reg) {
            int rloc = wr * 64 + mi * 16 + (lane >> 4) * 4 + reg;
            float thrT = fminf(rowmin[rloc][0], rowmin[rloc][1]) + EPS;
            float rsqv = rsq[mbase + rloc];
#pragma unroll
            for (int ni = 0; ni < 4; ++ni) {
                int kg = nbase + wc * 64 + ni * 16 + (lane & 15);
                float y;
                {
#pragma clang fp contract(off)
                    float t2 = 2.0f * acc[mi][ni][reg];
                    float u  = rsqv - t2;
                    y        = u + cb_sq[kg];
                }
                if (y <= thrT) {
                    int pos = atomicAdd(&scnt[rloc], 1);
                    if (pos < CAP)
                        sbuf[rloc * CAP + pos] =
                            ((unsigned long long)__float_as_uint(y) << 32) |
                            (unsigned)kg;
                }
            }
        }
    }
    __syncthreads();

    if (t < 128) {
        // [tile][row] layout: consecutive t -> consecutive rows -> contiguous.
        part[(size_t)jb * N_ROWS + (mbase + t)] =
            fminf(rowmin[t][0], rowmin[t][1]);
        unsigned long long s0 = sbuf[t * CAP + 0];
        unsigned long long s1 = sbuf[t * CAP + 1];
        if (scnt[t] > CAP) s0 = OVFL_E;
        size_t bidx = ((size_t)jb * N_ROWS + (mbase + t)) * CAP;
        gbuf[bidx]     = s0;
        gbuf[bidx + 1] = s1;
    }
}

// Pass BC (fused): lane-per-(row,tile); width-32 min of tile mins -> thr;
// surviving lanes run their <=2 exact chains INLINE; width-32 lexicographic
// packed-u64 reduce; plain best store. Overflow tiles -> bent fallback.
__global__ __launch_bounds__(256)
void passBC_kernel(const float* __restrict__ res,
                   const float* __restrict__ cb,
                   const float* __restrict__ cb_sq,
                   const float* __restrict__ rsq,
                   const float* __restrict__ part,
                   const unsigned long long* __restrict__ gbuf,
                   int* __restrict__ bcnt, int* __restrict__ bent,
                   unsigned long long* __restrict__ best) {
    const int t   = threadIdx.x;
    const int jr  = t & 31;                  // tile index
    const int rs  = t >> 5;                  // 0..7
    const int row = blockIdx.x * 8 + rs;

    float pv = part[(size_t)jr * N_ROWS + row];
    float m = pv;
#pragma unroll
    for (int off = 1; off < 32; off <<= 1)
        m = fminf(m, __shfl_xor(m, off, 32));   // width 32: per-row group
    const float thr = m + EPS;

    float by = INFINITY; int bk = 0x7fffffff;

    if (pv <= thr) {
        size_t bidx = ((size_t)jr * N_ROWS + row) * CAP;
        unsigned long long s0 = gbuf[bidx];
        unsigned long long s1 = gbuf[bidx + 1];
        if (s0 == OVFL_E) {                  // rare: full-tile fallback
            int pos = atomicAdd(&bcnt[jr], 1);
            bent[(size_t)jr * N_ROWS + pos] = row;
        } else {
            const float* rr  = res + (size_t)row * DIM;
            const float rsqv = rsq[row];
#pragma unroll
            for (int sl = 0; sl < CAP; ++sl) {
                unsigned long long s = sl ? s1 : s0;
                float yh = __uint_as_float((unsigned)(s >> 32));
                if (!(yh <= thr)) continue;  // EMPTY -> NaN -> skipped
                int k = (int)(s & 0xFFFFFFFFull);
                const float* wp = cb + (size_t)k * DIM;
                // Exact chain: one fmaf per d, d = 0..511 ascending.
                float dot = 0.0f;
#pragma unroll 8
                for (int d = 0; d < DIM; d += 4) {
                    float4 r4 = *(const float4*)(rr + d);
                    float4 w4 = *(const float4*)(wp + d);
                    dot = fmaf(r4.x, w4.x, dot);
                    dot = fmaf(r4.y, w4.y, dot);
                    dot = fmaf(r4.z, w4.z, dot);
                    dot = fmaf(r4.w, w4.w, dot);
                }
                float y;
                {
#pragma clang fp contract(off)
                    float t2 = 2.0f * dot;
                    float u  = rsqv - t2;
                    y        = u + cb_sq[k];
                }
                if (y < by || (y == by && k < bk)) { by = y; bk = k; }
            }
        }
    }

    // Lexicographic (y,k) reduce across the 32 jr lanes (packed u64 min).
    unsigned long long pk =
        ((unsigned long long)__float_as_uint(by) << 32) | (unsigned)bk;
#pragma unroll
    for (int off = 1; off < 32; off <<= 1) {
        unsigned long long o =
            (unsigned long long)__shfl_xor((long long)pk, off, 32);
        if (o < pk) pk = o;
    }
    if (jr == 0) best[row] = pk;   // plain store; passC atomicMins after
}

// Fallback pass C (round-13 verbatim): exact full-tile recheck of overflow
// entries (rare).
__global__ __launch_bounds__(256)
void passC_kernel(const float* __restrict__ res,
                  const float* __restrict__ cb,
                  const float* __restrict__ cb_sq,
                  const float* __restrict__ rsq,
                  const int* __restrict__ bcnt, const int* __restrict__ bent,
                  unsigned long long* __restrict__ best) {
    const int j   = blockIdx.x;
    const int cnt = bcnt[j];
    const int t   = threadIdx.x;
    const int cg  = t & 31;
    const int rg  = t >> 5;

    __shared__ __align__(16) float Ws[128 * WSTRC];
    __shared__ __align__(16) float Rs[CROWS * RSTR];
    __shared__ int   rowl[CROWS];
    __shared__ float rsql[CROWS];

    for (int base = blockIdx.y * CROWS; base < cnt; base += gridDim.y * CROWS) {
        if (t < CROWS) {
            int e  = base + t;
            int rw = bent[(size_t)j * N_ROWS + (e < cnt ? e : cnt - 1)];
            rowl[t] = rw;
            rsql[t] = rsq[rw];
        }
        __syncthreads();
        const int nrows = min(CROWS, cnt - base);

        float acc[4][4];
#pragma unroll
        for (int ri = 0; ri < 4; ++ri)
#pragma unroll
            for (int q = 0; q < 4; ++q) acc[ri][q] = 0.0f;

        for (int d0 = 0; d0 < DIM; d0 += 64) {
#pragma unroll
            for (int p = 0; p < 8; ++p) {
                int idx  = p * 256 + t;
                int cand = idx >> 4;
                int d4   = idx & 15;
                float4 v = *(const float4*)(cb + (size_t)(j * 128 + cand) * DIM + d0 + d4 * 4);
                int s = d4 ^ ((cand >> 2) & 7) ^ ((cand >> 5) & 3);
                *(float4*)&Ws[cand * WSTRC + s * 4] = v;
            }
#pragma unroll
            for (int p = 0; p < 2; ++p) {
                int idx = p * 256 + t;
                int row = idx >> 4;
                int d4  = idx & 15;
                float4 v = *(const float4*)(res + (size_t)rowl[row] * DIM + d0 + d4 * 4);
                *(float4*)&Rs[row * RSTR + d4 * 4] = v;
            }
            __syncthreads();

#pragma unroll
            for (int dq = 0; dq < 16; ++dq) {
                const int s = dq ^ (cg & 7) ^ ((cg >> 3) & 3);
                float4 w4[4];
#pragma unroll
                for (int q = 0; q < 4; ++q)
                    w4[q] = *(const float4*)&Ws[(cg * 4 + q) * WSTRC + s * 4];
#pragma unroll
                for (int ri = 0; ri < 4; ++ri) {
                    float4 rf = *(const float4*)&Rs[(rg * 4 + ri) * RSTR + dq * 4];
#pragma unroll
                    for (int dd = 0; dd < 4; ++dd) {
                        float rv = f4c(rf, dd);
                        acc[ri][0] = fmaf(rv, f4c(w4[0], dd), acc[ri][0]);
                        acc[ri][1] = fmaf(rv, f4c(w4[1], dd), acc[ri][1]);
                        acc[ri][2] = fmaf(rv, f4c(w4[2], dd), acc[ri][2]);
                        acc[ri][3] = fmaf(rv, f4c(w4[3], dd), acc[ri][3]);
                    }
                }
            }
            __syncthreads();
        }

#pragma unroll
        for (int ri = 0; ri < 4; ++ri) {
            int rloc = rg * 4 + ri;
            float rsqv = rsql[rloc];
            float by = INFINITY; int bk = 0x7fffffff;
#pragma unroll
            for (int q = 0; q < 4; ++q) {
                int k = j * 128 + cg * 4 + q;
                float y;
                {
#pragma clang fp contract(off)
                    float t2 = 2.0f * acc[ri][q];
                    float u  = rsqv - t2;
                    y        = u + cb_sq[k];
                }
                if (y < by || (y == by && k < bk)) { by = y; bk = k; }
            }
#pragma unroll
            for (int off = 1; off < 32; off <<= 1) {
                float ov = __shfl_xor(by, off, 64);
                int   oi = __shfl_xor(bk, off, 64);
                if (ov < by || (ov == by && oi < bk)) { by = ov; bk = oi; }
            }
            if (cg == 0 && rloc < nrows) {
                unsigned long long pk =
                    ((unsigned long long)__float_as_uint(by) << 32) |
                    (unsigned long long)(unsigned)bk;
                atomicMin(&best[rowl[rloc]], pk);
            }
        }
        __syncthreads();
    }
}

// Combine: best index -> idx_out; exact fp32 residual/q_ste update; for the
// next stage also emit rh, rsq, and zero bcnt.
__global__ __launch_bounds__(256)
void combine_kernel(float* __restrict__ res_out,
                    const float* __restrict__ res_in,
                    const float* __restrict__ cb,
                    const unsigned long long* __restrict__ best,
                    float* __restrict__ qout,
                    float* __restrict__ idx_out,
                    unsigned short* __restrict__ rh,
                    float* __restrict__ rsq,
                    int* __restrict__ bcnt,
                    int stage, int do_next) {
#pragma clang fp contract(off)
    const int t    = threadIdx.x;
    if (do_next && blockIdx.x == 0 && t < KTILES) bcnt[t] = 0;
    const int lane = t & 63;
    const int sub  = t >> 6;
    const int row  = blockIdx.x * 4 + sub;

    int bi = (int)(best[row] & 0xffffffffull);
    if (lane == 0) idx_out[(size_t)row * NUM_STAGES + stage] = (float)bi;

    const float* w   = cb + (size_t)bi * DIM;
    const float* rin = res_in + (size_t)row * DIM;
    float*       r   = res_out + (size_t)row * DIM;
    float*       q   = qout + (size_t)row * DIM;
    unsigned short* rhp = rh + (size_t)row * DIM;

    float rn8[8];
#pragma unroll
    for (int i = 0; i < DIM / 64; ++i) {
        int d = lane + i * 64;
        float wv = w[d];
        float rv = rin[d];
        float tq    = wv - rv;     // fl(q - r)
        float q_ste = rv + tq;     // fl(r + (q - r))
        float rn    = rv - q_ste;  // fl(r - q_ste)
        rn8[i] = rn;
        if (do_next) {
            r[d]   = rn;
            rhp[d] = f2bf(rn);
        }
        if (stage == 0) q[d] = q_ste;
        else            q[d] = q[d] + q_ste;
    }
    if (do_next) {
        float s = rowsq_tree(rn8, lane);
        if (lane == 0) rsq[row] = s;
    }
}

extern "C" void kernel_launch(void* const* d_in, const int* in_sizes, int n_in,
                              void* d_out, int out_size, void* d_ws, size_t ws_size,
                              hipStream_t stream) {
    const float* input = (const float*)d_in[0];
    const float* cb    = (const float*)d_in[1];

    float* out_f   = (float*)d_out;
    float* qout    = out_f + Q_OFF;
    float* idx_out = out_f + IDX_OFF;
    float* loss    = out_f + LOSS_OFF;

    char* ws = (char*)d_ws;
    float*          residual = (float*)(ws + RES_OFF);
    unsigned short* rh       = (unsigned short*)(ws + RH_OFF);
    unsigned short* wh       = (unsigned short*)(ws + WH_OFF);
    float*          cb_sq    = (float*)(ws + CBSQ_OFF);
    float*          rsq      = (float*)(ws + RSQ_OFF);
    float*          part     = (float*)(ws + PART_OFF);
    unsigned long long* gbuf = (unsigned long long*)(ws + GBUF_OFF);
    int*            bcnt     = (int*)(ws + BCNT_OFF);
    int*            bent     = (int*)(ws + BENT_OFF);
    unsigned long long* best = (unsigned long long*)(ws + BEST_OFF);

    cbsq_wh_kernel<<<K_CODES, 64, 0, stream>>>(cb, cb_sq, wh, loss);
    init_kernel<<<N_ROWS / 4, 256, 0, stream>>>(input, rh, rsq, bcnt);

    for (int s = 0; s < NUM_STAGES; ++s) {
        const float* rin = (s == 0) ? input : residual;
        passA_kernel<<<dim3(KTILES, N_ROWS / 128), 256, 0, stream>>>(
            rh, wh, cb_sq, rsq, part, gbuf);
        passBC_kernel<<<N_ROWS / 8, 256, 0, stream>>>(
            rin, cb, cb_sq, rsq, part, gbuf, bcnt, bent, best);
        passC_kernel<<<dim3(KTILES, CGRIDY), 256, 0, stream>>>(
            rin, cb, cb_sq, rsq, bcnt, bent, best);
        combine_kernel<<<N_ROWS / 4, 256, 0, stream>>>(
            residual, rin, cb, best, qout, idx_out, rh, rsq, bcnt,
            s, (s < NUM_STAGES - 1) ? 1 : 0);
    }
}

// Round 17
// 896.131 us; speedup vs baseline: 2.3720x; 1.0746x over previous
//
#include <hip/hip_runtime.h>
#include <math.h>

// Residual VQ, 4 stages, N=16384 rows, D=512, K=4096.
// Round 17: two targeted fixes on the r16 structure (PASSED, 963us):
//   passA: XCD-aware block swizzle (xcd=lin&7 owns mb in [16*xcd,16*xcd+16))
//          -> per-XCD A-panel working set 2MB + B 4MB, both L2-resident
//          (was: all 16MB of A streaming through every XCD L2; FETCH 68.5MB).
//   passBC: count-1 shortcut -- if exactly one candidate has y^ <= gmin+EPS
//          and no tile overflowed, it IS the argmin (containment proof,
//          rounds 7-16); skip the exact chain. ~50% of rows qualify.
// Exact-math invariants (verified rounds 3-16): one fmaf per d, d=0..511
// ascending, per output; epilogue fl(fl(rsq-fl(2*dot))+cbsq) uncontracted;
// first-index ties; numpy pairwise rsq/cbsq tree; exact residual/q_ste chain.

namespace {
constexpr int N_ROWS     = 16384;
constexpr int DIM        = 512;
constexpr int K_CODES    = 4096;
constexpr int NUM_STAGES = 4;

constexpr int KTILES = 32;            // 128 codes per tile
constexpr int LTS    = 72;            // passA LDS row stride (bf16 elems)
constexpr float EPS  = 1e-3f;         // candidate margin (proven rounds 7-16)
constexpr int CAP    = 2;             // compacted candidates per (row,tile)

constexpr int CROWS  = 32;            // fallback passC rows per batch
constexpr int CGRIDY = 8;             // fallback passC y-blocks per ktile
constexpr int WSTRC  = 68;            // fallback passC Ws row stride (dwords)
constexpr int RSTR   = 68;            // fallback passC Rs row stride (dwords)

// d_out layout (all read back as float32):
constexpr size_t Q_OFF    = 0;
constexpr size_t IDX_OFF  = (size_t)N_ROWS * DIM;                  // 8388608
constexpr size_t LOSS_OFF = IDX_OFF + (size_t)N_ROWS * NUM_STAGES; // 8454144

// ws layout (bytes), total ~64.3 MB:
constexpr size_t RES_OFF  = 0;                                    // 32 MB fp32 residual
constexpr size_t RH_OFF   = (size_t)N_ROWS * DIM * 4;             // +16 MB bf16 residual
constexpr size_t WH_OFF   = RH_OFF + (size_t)N_ROWS * DIM * 2;    // +4 MB bf16 codebook
constexpr size_t CBSQ_OFF = WH_OFF + (size_t)K_CODES * DIM * 2;   // +16 KB
constexpr size_t RSQ_OFF  = CBSQ_OFF + (size_t)K_CODES * 4;       // +64 KB
constexpr size_t PART_OFF = RSQ_OFF + (size_t)N_ROWS * 4;         // +2 MB tile mins [tile][row]
constexpr size_t GBUF_OFF = PART_OFF + (size_t)N_ROWS * KTILES * 4;       // +8 MB [tile][row][CAP]
constexpr size_t BCNT_OFF = GBUF_OFF + (size_t)N_ROWS * KTILES * CAP * 8; // +128 B
constexpr size_t BENT_OFF = BCNT_OFF + 128;                       // +2 MB overflow lists
constexpr size_t BEST_OFF = BENT_OFF + (size_t)KTILES * N_ROWS * 4; // +128 KB packed best

constexpr unsigned long long EMPTY_E = 0xFFFFFFFFFFFFFFFFull;
constexpr unsigned long long OVFL_E  = 0xFFFFFFFFFFFFFFFEull;
} // namespace

typedef short bf16x8 __attribute__((ext_vector_type(8)));
typedef float f32x4  __attribute__((ext_vector_type(4)));

__device__ __forceinline__ unsigned short f2bf(float x) {   // RNE fp32->bf16
    unsigned int u = __float_as_uint(x);
    return (unsigned short)((u + 0x7fffu + ((u >> 16) & 1u)) >> 16);
}

__device__ __forceinline__ float f4c(const float4& v, int q) {
    return q == 0 ? v.x : q == 1 ? v.y : q == 2 ? v.z : v.w;
}

// Register-based exact pairwise tree: v8[i] = row[lane + i*64], i=0..7.
__device__ __forceinline__ float rowsq_tree(const float v8[8], int lane) {
#pragma clang fp contract(off)
    float P[4];
#pragma unroll
    for (int b = 0; b < 4; ++b) {
        float xa = v8[2 * b];
        float xb = v8[2 * b + 1];
        float sa = xa * xa;
        float sb = xb * xb;
        float R  = sa + sb;
        float t  = R + __shfl_down(R, 16, 64);
        float u  = t + __shfl_down(t, 32, 64);
        float a  = u + __shfl_down(u, 8, 64);
        float c  = a + __shfl_down(a, 4, 64);
        float d  = c + __shfl_down(c, 2, 64);
        P[b]     = d + __shfl_down(d, 1, 64);
    }
    float s01 = P[0] + P[1];
    float s23 = P[2] + P[3];
    return s01 + s23;
}

// cbsq + codebook bf16 conversion, fused.
__global__ __launch_bounds__(64)
void cbsq_wh_kernel(const float* __restrict__ cb, float* __restrict__ cb_sq,
                    unsigned short* __restrict__ wh, float* __restrict__ loss) {
    int k = blockIdx.x;
    int lane = threadIdx.x;
    const float* row = cb + (size_t)k * DIM;
    unsigned short* whp = wh + (size_t)k * DIM;
    float v8[8];
#pragma unroll
    for (int i = 0; i < 8; ++i) {
        float v = row[lane + i * 64];
        v8[i] = v;
        whp[lane + i * 64] = f2bf(v);
    }
    float s = rowsq_tree(v8, lane);
    if (lane == 0) cb_sq[k] = s;
    if (k == 0 && lane == 0) *loss = 0.0f;
}

// Stage-0 init: rh = bf16(input), rsq = pairwise(input), zero bcnt.
__global__ __launch_bounds__(256)
void init_kernel(const float* __restrict__ input,
                 unsigned short* __restrict__ rh,
                 float* __restrict__ rsq, int* __restrict__ bcnt) {
    const int t = threadIdx.x;
    if (blockIdx.x == 0 && t < KTILES) bcnt[t] = 0;
    const int lane = t & 63;
    const int sub  = t >> 6;
    const int row  = blockIdx.x * 4 + sub;
    const float* x = input + (size_t)row * DIM;
    unsigned short* rhp = rh + (size_t)row * DIM;
    float v8[8];
#pragma unroll
    for (int i = 0; i < 8; ++i) {
        int d = lane + i * 64;
        float v = x[d];
        v8[i] = v;
        rhp[d] = f2bf(v);
    }
    float s = rowsq_tree(v8, lane);
    if (lane == 0) rsq[row] = s;
}

// Pass A: 128x128x(BK=64) bf16 MFMA GEMM + epilogue candidate compaction.
// XCD-aware swizzle: xcd = lin&7 owns mb in [16*xcd, 16*xcd+16) -> per-XCD
// A working set 2MB + B 4MB, both L2-resident. Bijective (4096 % 8 == 0).
__global__ __launch_bounds__(256, 2)
void passA_kernel(const unsigned short* __restrict__ rh,
                  const unsigned short* __restrict__ wh,
                  const float* __restrict__ cb_sq,
                  const float* __restrict__ rsq,
                  float* __restrict__ part,
                  unsigned long long* __restrict__ gbuf) {
    const int lin = blockIdx.x + KTILES * blockIdx.y;
    const int xcd = lin & 7;
    const int c   = lin >> 3;               // 0..511
    const int jb  = c & 31;                 // ktile
    const int mb  = xcd * 16 + (c >> 5);    // row tile: contiguous per XCD
    const int mbase = mb * 128;
    const int nbase = jb * 128;

    __shared__ __align__(16) unsigned short At[128 * LTS];
    __shared__ __align__(16) unsigned short Bt[128 * LTS];
    __shared__ float rowmin[128][2];

    const int t    = threadIdx.x;
    const int lane = t & 63;
    const int wid  = t >> 6;
    const int wr   = wid >> 1;
    const int wc   = wid & 1;

    f32x4 acc[4][4];
#pragma unroll
    for (int mi = 0; mi < 4; ++mi)
#pragma unroll
        for (int ni = 0; ni < 4; ++ni) acc[mi][ni] = (f32x4){0.f, 0.f, 0.f, 0.f};

    for (int k0 = 0; k0 < DIM; k0 += 64) {
#pragma unroll
        for (int p = 0; p < 4; ++p) {
            int idx = p * 256 + t;
            int row = idx >> 3;
            int d8  = idx & 7;
            uint4 va = *(const uint4*)(rh + (size_t)(mbase + row) * DIM + k0 + d8 * 8);
            *(uint4*)&At[row * LTS + d8 * 8] = va;
            uint4 vb = *(const uint4*)(wh + (size_t)(nbase + row) * DIM + k0 + d8 * 8);
            *(uint4*)&Bt[row * LTS + d8 * 8] = vb;
        }
        __syncthreads();

#pragma unroll
        for (int kk = 0; kk < 2; ++kk) {
            bf16x8 af[4], bfr[4];
#pragma unroll
            for (int mi = 0; mi < 4; ++mi)
                af[mi] = *(const bf16x8*)&At[(wr * 64 + mi * 16 + (lane & 15)) * LTS
                                             + kk * 32 + (lane >> 4) * 8];
#pragma unroll
            for (int ni = 0; ni < 4; ++ni)
                bfr[ni] = *(const bf16x8*)&Bt[(wc * 64 + ni * 16 + (lane & 15)) * LTS
                                              + kk * 32 + (lane >> 4) * 8];
#pragma unroll
            for (int mi = 0; mi < 4; ++mi)
#pragma unroll
                for (int ni = 0; ni < 4; ++ni)
                    acc[mi][ni] = __builtin_amdgcn_mfma_f32_16x16x32_bf16(
                        af[mi], bfr[ni], acc[mi][ni], 0, 0, 0);
        }
        __syncthreads();
    }

    int* scnt = (int*)Bt;
    unsigned long long* sbuf = (unsigned long long*)At;
    if (t < 128) {
        scnt[t] = 0;
        sbuf[t * CAP + 0] = EMPTY_E;
        sbuf[t * CAP + 1] = EMPTY_E;
    }

    // Pass 1: per-row tile min.
#pragma unroll
    for (int mi = 0; mi < 4; ++mi) {
#pragma unroll
        for (int reg = 0; reg < 4; ++reg) {
            int rloc = wr * 64 + mi * 16 + (lane >> 4) * 4 + reg;
            float rsqv = rsq[mbase + rloc];
            float m = INFINITY;
#pragma unroll
            for (int ni = 0; ni < 4; ++ni) {
                int kg = nbase + wc * 64 + ni * 16 + (lane & 15);
                float y;
                {
#pragma clang fp contract(off)
                    float t2 = 2.0f * acc[mi][ni][reg];
                    float u  = rsqv - t2;
                    y        = u + cb_sq[kg];
                }
                m = fminf(m, y);
            }
#pragma unroll
            for (int off = 1; off < 16; off <<= 1)
                m = fminf(m, __shfl_xor(m, off, 64));
            if ((lane & 15) == 0) rowmin[rloc][wc] = m;
        }
    }
    __syncthreads();

    // Pass 2: compact candidates with y <= tilemin + EPS.
#pragma unroll
    for (int mi = 0; mi < 4; ++mi) {
#pragma unroll
        for (int reg = 0; reg < 4; ++reg) {
            int rloc = wr * 64 + mi * 16 + (lane >> 4) * 4 + reg;
            float thrT = fminf(rowmin[rloc][0], rowmin[rloc][1]) + EPS;
            float rsqv = rsq[mbase + rloc];
#pragma unroll
            for (int ni = 0; ni < 4; ++ni) {
                int kg = nbase + wc * 64 + ni * 16 + (lane & 15);
                float y;
                {
#pragma clang fp contract(off)
                    float t2 = 2.0f * acc[mi][ni][reg];
                    float u  = rsqv - t2;
                    y        = u + cb_sq[kg];
                }
                if (y <= thrT) {
                    int pos = atomicAdd(&scnt[rloc], 1);
                    if (pos < CAP)
                        sbuf[rloc * CAP + pos] =
                            ((unsigned long long)__float_as_uint(y) << 32) |
                            (unsigned)kg;
                }
            }
        }
    }
    __syncthreads();

    if (t < 128) {
        part[(size_t)jb * N_ROWS + (mbase + t)] =
            fminf(rowmin[t][0], rowmin[t][1]);
        unsigned long long s0 = sbuf[t * CAP + 0];
        unsigned long long s1 = sbuf[t * CAP + 1];
        if (scnt[t] > CAP) s0 = OVFL_E;
        size_t bidx = ((size_t)jb * N_ROWS + (mbase + t)) * CAP;
        gbuf[bidx]     = s0;
        gbuf[bidx + 1] = s1;
    }
}

// Pass BC: lane-per-(row,tile); width-32 min -> thr; COUNT-1 SHORTCUT: if
// exactly one candidate qualifies row-wide and no tile overflowed, it is the
// argmin (containment) -> store directly, no exact chain. Else inline exact
// chains + width-32 packed-u64 reduce. Overflow tiles -> bent fallback.
__global__ __launch_bounds__(256)
void passBC_kernel(const float* __restrict__ res,
                   const float* __restrict__ cb,
                   const float* __restrict__ cb_sq,
                   const float* __restrict__ rsq,
                   const float* __restrict__ part,
                   const unsigned long long* __restrict__ gbuf,
                   int* __restrict__ bcnt, int* __restrict__ bent,
                   unsigned long long* __restrict__ best) {
    const int t   = threadIdx.x;
    const int jr  = t & 31;                  // tile index
    const int rs  = t >> 5;                  // 0..7
    const int row = blockIdx.x * 8 + rs;

    float pv = part[(size_t)jr * N_ROWS + row];
    float m = pv;
#pragma unroll
    for (int off = 1; off < 32; off <<= 1)
        m = fminf(m, __shfl_xor(m, off, 32));   // width 32: per-row group
    const float thr = m + EPS;

    unsigned long long s0 = EMPTY_E, s1 = EMPTY_E;
    bool surv = (pv <= thr);
    if (surv) {
        size_t bidx = ((size_t)jr * N_ROWS + row) * CAP;
        s0 = gbuf[bidx];
        s1 = gbuf[bidx + 1];
    }
    const bool ovfl = surv && (s0 == OVFL_E);
    if (ovfl) {                              // rare: full-tile fallback
        int pos = atomicAdd(&bcnt[jr], 1);
        bent[(size_t)jr * N_ROWS + pos] = row;
    }

    // Lane-local qualifying count + candidate (packed slot value).
    int lcl = 0;
    unsigned long long cand = EMPTY_E;
    float y0 = __uint_as_float((unsigned)(s0 >> 32));   // EMPTY/OVFL -> NaN
    float y1 = __uint_as_float((unsigned)(s1 >> 32));
    if (surv && !ovfl) {
        if (y0 <= thr) { lcl++; cand = s0; }
        if (y1 <= thr) { lcl++; cand = s1; }
    }
    int tot = lcl;
    int oc  = ovfl ? 1 : 0;
#pragma unroll
    for (int off = 1; off < 32; off <<= 1) {
        tot += __shfl_xor(tot, off, 32);
        oc  += __shfl_xor(oc, off, 32);
    }

    if (tot == 1 && oc == 0) {
        // Unique candidate == true argmin; no exact chain needed.
        if (lcl == 1) best[row] = cand;
        return;
    }

    // General path: exact chains for local qualifying slots.
    float by = INFINITY; int bk = 0x7fffffff;
    if (surv && !ovfl && lcl > 0) {
        const float* rr  = res + (size_t)row * DIM;
        const float rsqv = rsq[row];
#pragma unroll
        for (int sl = 0; sl < CAP; ++sl) {
            unsigned long long s = sl ? s1 : s0;
            float yh = __uint_as_float((unsigned)(s >> 32));
            if (!(yh <= thr)) continue;      // EMPTY -> NaN -> skipped
            int k = (int)(s & 0xFFFFFFFFull);
            const float* wp = cb + (size_t)k * DIM;
            float dot = 0.0f;                // exact chain, d ascending
#pragma unroll 8
            for (int d = 0; d < DIM; d += 4) {
                float4 r4 = *(const float4*)(rr + d);
                float4 w4 = *(const float4*)(wp + d);
                dot = fmaf(r4.x, w4.x, dot);
                dot = fmaf(r4.y, w4.y, dot);
                dot = fmaf(r4.z, w4.z, dot);
                dot = fmaf(r4.w, w4.w, dot);
            }
            float y;
            {
#pragma clang fp contract(off)
                float t2 = 2.0f * dot;
                float u  = rsqv - t2;
                y        = u + cb_sq[k];
            }
            if (y < by || (y == by && k < bk)) { by = y; bk = k; }
        }
    }

    unsigned long long pk =
        ((unsigned long long)__float_as_uint(by) << 32) | (unsigned)bk;
#pragma unroll
    for (int off = 1; off < 32; off <<= 1) {
        unsigned long long o =
            (unsigned long long)__shfl_xor((long long)pk, off, 32);
        if (o < pk) pk = o;
    }
    if (jr == 0) best[row] = pk;   // plain store; passC atomicMins after
}

// Fallback pass C (round-13 verbatim): exact full-tile recheck of overflow
// entries (rare).
__global__ __launch_bounds__(256)
void passC_kernel(const float* __restrict__ res,
                  const float* __restrict__ cb,
                  const float* __restrict__ cb_sq,
                  const float* __restrict__ rsq,
                  const int* __restrict__ bcnt, const int* __restrict__ bent,
                  unsigned long long* __restrict__ best) {
    const int j   = blockIdx.x;
    const int cnt = bcnt[j];
    const int t   = threadIdx.x;
    const int cg  = t & 31;
    const int rg  = t >> 5;

    __shared__ __align__(16) float Ws[128 * WSTRC];
    __shared__ __align__(16) float Rs[CROWS * RSTR];
    __shared__ int   rowl[CROWS];
    __shared__ float rsql[CROWS];

    for (int base = blockIdx.y * CROWS; base < cnt; base += gridDim.y * CROWS) {
        if (t < CROWS) {
            int e  = base + t;
            int rw = bent[(size_t)j * N_ROWS + (e < cnt ? e : cnt - 1)];
            rowl[t] = rw;
            rsql[t] = rsq[rw];
        }
        __syncthreads();
        const int nrows = min(CROWS, cnt - base);

        float acc[4][4];
#pragma unroll
        for (int ri = 0; ri < 4; ++ri)
#pragma unroll
            for (int q = 0; q < 4; ++q) acc[ri][q] = 0.0f;

        for (int d0 = 0; d0 < DIM; d0 += 64) {
#pragma unroll
            for (int p = 0; p < 8; ++p) {
                int idx  = p * 256 + t;
                int cand = idx >> 4;
                int d4   = idx & 15;
                float4 v = *(const float4*)(cb + (size_t)(j * 128 + cand) * DIM + d0 + d4 * 4);
                int s = d4 ^ ((cand >> 2) & 7) ^ ((cand >> 5) & 3);
                *(float4*)&Ws[cand * WSTRC + s * 4] = v;
            }
#pragma unroll
            for (int p = 0; p < 2; ++p) {
                int idx = p * 256 + t;
                int row = idx >> 4;
                int d4  = idx & 15;
                float4 v = *(const float4*)(res + (size_t)rowl[row] * DIM + d0 + d4 * 4);
                *(float4*)&Rs[row * RSTR + d4 * 4] = v;
            }
            __syncthreads();

#pragma unroll
            for (int dq = 0; dq < 16; ++dq) {
                const int s = dq ^ (cg & 7) ^ ((cg >> 3) & 3);
                float4 w4[4];
#pragma unroll
                for (int q = 0; q < 4; ++q)
                    w4[q] = *(const float4*)&Ws[(cg * 4 + q) * WSTRC + s * 4];
#pragma unroll
                for (int ri = 0; ri < 4; ++ri) {
                    float4 rf = *(const float4*)&Rs[(rg * 4 + ri) * RSTR + dq * 4];
#pragma unroll
                    for (int dd = 0; dd < 4; ++dd) {
                        float rv = f4c(rf, dd);
                        acc[ri][0] = fmaf(rv, f4c(w4[0], dd), acc[ri][0]);
                        acc[ri][1] = fmaf(rv, f4c(w4[1], dd), acc[ri][1]);
                        acc[ri][2] = fmaf(rv, f4c(w4[2], dd), acc[ri][2]);
                        acc[ri][3] = fmaf(rv, f4c(w4[3], dd), acc[ri][3]);
                    }
                }
            }
            __syncthreads();
        }

#pragma unroll
        for (int ri = 0; ri < 4; ++ri) {
            int rloc = rg * 4 + ri;
            float rsqv = rsql[rloc];
            float by = INFINITY; int bk = 0x7fffffff;
#pragma unroll
            for (int q = 0; q < 4; ++q) {
                int k = j * 128 + cg * 4 + q;
                float y;
                {
#pragma clang fp contract(off)
                    float t2 = 2.0f * acc[ri][q];
                    float u  = rsqv - t2;
                    y        = u + cb_sq[k];
                }
                if (y < by || (y == by && k < bk)) { by = y; bk = k; }
            }
#pragma unroll
            for (int off = 1; off < 32; off <<= 1) {
                float ov = __shfl_xor(by, off, 64);
                int   oi = __shfl_xor(bk, off, 64);
                if (ov < by || (ov == by && oi < bk)) { by = ov; bk = oi; }
            }
            if (cg == 0 && rloc < nrows) {
                unsigned long long pk =
                    ((unsigned long long)__float_as_uint(by) << 32) |
                    (unsigned long long)(unsigned)bk;
                atomicMin(&best[rowl[rloc]], pk);
            }
        }
        __syncthreads();
    }
}

// Combine: best index -> idx_out; exact fp32 residual/q_ste update; for the
// next stage also emit rh, rsq, and zero bcnt.
__global__ __launch_bounds__(256)
void combine_kernel(float* __restrict__ res_out,
                    const float* __restrict__ res_in,
                    const float* __restrict__ cb,
                    const unsigned long long* __restrict__ best,
                    float* __restrict__ qout,
                    float* __restrict__ idx_out,
                    unsigned short* __restrict__ rh,
                    float* __restrict__ rsq,
                    int* __restrict__ bcnt,
                    int stage, int do_next) {
#pragma clang fp contract(off)
    const int t    = threadIdx.x;
    if (do_next && blockIdx.x == 0 && t < KTILES) bcnt[t] = 0;
    const int lane = t & 63;
    const int sub  = t >> 6;
    const int row  = blockIdx.x * 4 + sub;

    int bi = (int)(best[row] & 0xffffffffull);
    if (lane == 0) idx_out[(size_t)row * NUM_STAGES + stage] = (float)bi;

    const float* w   = cb + (size_t)bi * DIM;
    const float* rin = res_in + (size_t)row * DIM;
    float*       r   = res_out + (size_t)row * DIM;
    float*       q   = qout + (size_t)row * DIM;
    unsigned short* rhp = rh + (size_t)row * DIM;

    float rn8[8];
#pragma unroll
    for (int i = 0; i < DIM / 64; ++i) {
        int d = lane + i * 64;
        float wv = w[d];
        float rv = rin[d];
        float tq    = wv - rv;     // fl(q - r)
        float q_ste = rv + tq;     // fl(r + (q - r))
        float rn    = rv - q_ste;  // fl(r - q_ste)
        rn8[i] = rn;
        if (do_next) {
            r[d]   = rn;
            rhp[d] = f2bf(rn);
        }
        if (stage == 0) q[d] = q_ste;
        else            q[d] = q[d] + q_ste;
    }
    if (do_next) {
        float s = rowsq_tree(rn8, lane);
        if (lane == 0) rsq[row] = s;
    }
}

extern "C" void kernel_launch(void* const* d_in, const int* in_sizes, int n_in,
                              void* d_out, int out_size, void* d_ws, size_t ws_size,
                              hipStream_t stream) {
    const float* input = (const float*)d_in[0];
    const float* cb    = (const float*)d_in[1];

    float* out_f   = (float*)d_out;
    float* qout    = out_f + Q_OFF;
    float* idx_out = out_f + IDX_OFF;
    float* loss    = out_f + LOSS_OFF;

    char* ws = (char*)d_ws;
    float*          residual = (float*)(ws + RES_OFF);
    unsigned short* rh       = (unsigned short*)(ws + RH_OFF);
    unsigned short* wh       = (unsigned short*)(ws + WH_OFF);
    float*          cb_sq    = (float*)(ws + CBSQ_OFF);
    float*          rsq      = (float*)(ws + RSQ_OFF);
    float*          part     = (float*)(ws + PART_OFF);
    unsigned long long* gbuf = (unsigned long long*)(ws + GBUF_OFF);
    int*            bcnt     = (int*)(ws + BCNT_OFF);
    int*            bent     = (int*)(ws + BENT_OFF);
    unsigned long long* best = (unsigned long long*)(ws + BEST_OFF);

    cbsq_wh_kernel<<<K_CODES, 64, 0, stream>>>(cb, cb_sq, wh, loss);
    init_kernel<<<N_ROWS / 4, 256, 0, stream>>>(input, rh, rsq, bcnt);

    for (int s = 0; s < NUM_STAGES; ++s) {
        const float* rin = (s == 0) ? input : residual;
        passA_kernel<<<dim3(KTILES, N_ROWS / 128), 256, 0, stream>>>(
            rh, wh, cb_sq, rsq, part, gbuf);
        passBC_kernel<<<N_ROWS / 8, 256, 0, stream>>>(
            rin, cb, cb_sq, rsq, part, gbuf, bcnt, bent, best);
        passC_kernel<<<dim3(KTILES, CGRIDY), 256, 0, stream>>>(
            rin, cb, cb_sq, rsq, bcnt, bent, best);
        combine_kernel<<<N_ROWS / 4, 256, 0, stream>>>(
            residual, rin, cb, best, qout, idx_out, rh, rsq, bcnt,
            s, (s < NUM_STAGES - 1) ? 1 : 0);
    }
}